// Round 8
// baseline (249.342 us; speedup 1.0000x reference)
//
#include <hip/hip_runtime.h>
#include <math.h>

#define NEG_SLOPE 0.2f

typedef __attribute__((ext_vector_type(8))) short short8;   // 8 bf16 (4 VGPRs)
typedef __attribute__((ext_vector_type(4))) float f32x4;
typedef __attribute__((ext_vector_type(2))) float f32x2;

// ---------- helpers ----------
__device__ __forceinline__ float lrelu(float v) { return v > 0.f ? v : NEG_SLOPE * v; }
__device__ __forceinline__ float elu(float v) { return v > 0.f ? v : (__expf(v) - 1.f); }
__device__ __forceinline__ unsigned short f2b(float f) {   // fp32 -> bf16 RNE
    unsigned u = __float_as_uint(f);
    return (unsigned short)((u + 0x7FFFu + ((u >> 16) & 1u)) >> 16);
}
__device__ __forceinline__ unsigned packb(float a, float b) {
    return ((unsigned)f2b(b) << 16) | (unsigned)f2b(a);
}
// fp8 e4m3 (OCP, gfx950 HW converts)
__device__ __forceinline__ unsigned short pack8(float a, float b) {
    return (unsigned short)(__builtin_amdgcn_cvt_pk_fp8_f32(a, b, 0, false) & 0xFFFF);
}
__device__ __forceinline__ f32x2 unpack8(unsigned v) {
    return __builtin_amdgcn_cvt_pk_f32_fp8((int)v, false);
}
__device__ __forceinline__ f32x2 unpack8hi(unsigned v) {
    return __builtin_amdgcn_cvt_pk_f32_fp8((int)v, true);
}
// two f32 -> packed bf16 pair by truncation (exact when inputs came from fp8)
__device__ __forceinline__ unsigned bpack_trunc(f32x2 f) {
    return (__float_as_uint(f.y) & 0xFFFF0000u) | (__float_as_uint(f.x) >> 16);
}
// LDS xor-swizzle: 16B-chunk o within row r
__device__ __forceinline__ int sw(int r, int o) { return (o ^ (r & 7)) << 3; }

// ---------- prep v2: block-range split, coalesced LDS-tiled transposes ----------
// blocks [0,NH1): h1 gather (1 job/thread); [NH1,NH1+DEGB): degree count;
// next 16: W1t 64x64 tile transposes; next 9: W2t tile transposes.
__global__ __launch_bounds__(256) void prep_k(const int* __restrict__ x,
                       const int* __restrict__ et, const int* __restrict__ ei,
                       const float* __restrict__ ent_emb, const float* __restrict__ rel_emb,
                       const float* __restrict__ W1, const float* __restrict__ W2,
                       unsigned* __restrict__ h1b2, unsigned short* __restrict__ W1t,
                       unsigned short* __restrict__ W2t, unsigned char* __restrict__ h2q8,
                       int* __restrict__ deg, int N, int E, int NH1, int DEGB) {
    __shared__ float T[64 * 65];
    int bid = blockIdx.x, tid = threadIdx.x;
    if (bid < NH1) {              // ---- h1 construction ----
        int t = bid * 256 + tid;
        if (t < N * 64) {         // pair j: cols 2j, 2j+1 of h1=[ent|rel]
            int n = t >> 6, j = t & 63;
            float v0, v1;
            if (j < 32) {
                const float* e = ent_emb + (size_t)x[n] * 64 + 2 * j;
                v0 = e[0]; v1 = e[1];
                // ent fp8 -> h2 cols 512+2j, 512+2j+1 (row stride 576 B)
                *(unsigned short*)(h2q8 + (size_t)n * 576 + 512 + 2 * j) = pack8(v0, v1);
            } else {
                const float* r = rel_emb + (size_t)et[n] * 64 + 2 * (j - 32);
                v0 = r[0]; v1 = r[1];
            }
            h1b2[t] = packb(v0, v1);
        }
        return;
    }
    bid -= NH1;
    if (bid < DEGB) {             // ---- degree (incl self-loop); deg[] pre-zeroed ----
        int e = bid * 256 + tid;
        if (e < E + N) {
            int dst = e < E ? ei[E + e] : e - E;
            atomicAdd(&deg[dst], 1);
        }
        return;
    }
    bid -= DEGB;
    if (bid < 16) {               // ---- W1t[n][k] = W1[k][n]; W1 [128][512] f32 ----
        int kt = bid >> 3, nt = bid & 7;
        for (int c = tid; c < 4096; c += 256) {
            int r = c >> 6, o = c & 63;    // r: k in tile, o: n in tile (coalesced read)
            T[o * 65 + r] = W1[(size_t)(kt * 64 + r) * 512 + nt * 64 + o];
        }
        __syncthreads();
        for (int c = tid; c < 4096; c += 256) {
            int n = c >> 6, k = c & 63;    // coalesced 128B-row writes
            W1t[(size_t)(nt * 64 + n) * 128 + kt * 64 + k] = f2b(T[n * 65 + k]);
        }
        return;
    }
    bid -= 16;
    if (bid < 9) {                // ---- W2t[n][k] = W2[k][n]; W2 [576][64] f32 ----
        int kt = bid;
        for (int c = tid; c < 4096; c += 256) {
            int r = c >> 6, o = c & 63;
            T[o * 65 + r] = W2[(size_t)(kt * 64 + r) * 64 + o];
        }
        __syncthreads();
        for (int c = tid; c < 4096; c += 256) {
            int n = c >> 6, k = c & 63;
            W2t[(size_t)n * 576 + kt * 64 + k] = f2b(T[n * 65 + k]);
        }
        return;
    }
}

// ---------- single-dispatch decoupled-lookback scan: deg -> offs ----------
__global__ __launch_bounds__(256) void scan_k(const int* __restrict__ deg,
                                              int* __restrict__ offs,
                                              int* __restrict__ bstate,
                                              int N, int Etot, int NB) {
    __shared__ int s[256];
    __shared__ int sbase;
    int b = blockIdx.x, t = threadIdx.x;
    int i = b * 256 + t;
    int v = (i < N) ? deg[i] : 0;
    s[t] = v;
    __syncthreads();
    for (int off = 1; off < 256; off <<= 1) {
        int tmp = (t >= off) ? s[t - off] : 0;
        __syncthreads();
        s[t] += tmp;
        __syncthreads();
    }
    int total = s[255];
    if (t == 0) {
        if (b == 0) {
            atomicExch(&bstate[0], (total << 2) | 2);
            sbase = 0;
        } else {
            atomicExch(&bstate[b], (total << 2) | 1);
            int run = 0;
            for (int p = b - 1; p >= 0;) {
                int stv;
                do { stv = atomicAdd(&bstate[p], 0); } while ((stv & 3) == 0);
                run += (stv >> 2);
                if ((stv & 3) == 2) break;
                p--;
            }
            atomicExch(&bstate[b], ((run + total) << 2) | 2);
            sbase = run;
        }
    }
    __syncthreads();
    if (i < N) offs[i] = sbase + s[t] - v;
    if (b == NB - 1 && t == 0) offs[N] = Etot;
}

// ---------- merged: CSR fill (blocks < FB) | gemm1 (+fused attn1) (blocks >= FB) ----------
__global__ __launch_bounds__(256) void fillgemm1_k(const int* __restrict__ ei, int E, int N,
                                                   const int* __restrict__ offs,
                                                   int* __restrict__ cursor,
                                                   int* __restrict__ csr,
                                                   const unsigned short* __restrict__ A,
                                                   const unsigned short* __restrict__ W1t,
                                                   const float* __restrict__ a1s,
                                                   const float* __restrict__ a1d,
                                                   unsigned char* __restrict__ hl8,
                                                   float* __restrict__ als,
                                                   float* __restrict__ ald,
                                                   int FB, int NMB) {
    __shared__ __align__(16) unsigned char Cs[128 * 64];   // 8KB output staging
    int bid = blockIdx.x;
    int tid = threadIdx.x;
    if (bid < FB) {               // ---- CSR fill path (no barriers) ----
        int e = bid * 256 + tid;
        if (e < E + N) {
            int src = e < E ? ei[e] : e - E;
            int dst = e < E ? ei[E + e] : e - E;
            int pos = offs[dst] + atomicAdd(&cursor[dst], 1);
            csr[pos] = src;
        }
        return;
    }
    // ---- gemm1 path ----
    int g = bid - FB;
    int h = g / NMB, mb = g - h * NMB;
    int m0 = mb * 128;
    int M = N;
    int w = tid >> 6, lane = tid & 63;
    int wr = w * 32;
    int m16 = lane & 15, quad = lane >> 4;
    f32x4 acc[2][4] = {};
#pragma unroll
    for (int kk = 0; kk < 128; kk += 32) {
        int col = kk + quad * 8;                 // lane's 8-elem fragment column
        short8 b[4];
#pragma unroll
        for (int j = 0; j < 4; j++)
            b[j] = *(const short8*)(W1t + (size_t)(h * 64 + j * 16 + m16) * 128 + col);
#pragma unroll
        for (int i = 0; i < 2; i++) {
            int r = m0 + wr + i * 16 + m16;
            short8 a = {};
            if (r < M) a = *(const short8*)(A + (size_t)r * 128 + col);
#pragma unroll
            for (int j = 0; j < 4; j++)
                acc[i][j] = __builtin_amdgcn_mfma_f32_16x16x32_bf16(a, b[j], acc[i][j], 0, 0, 0);
        }
    }
    // fused attn1: als/ald = sum_col hl * a1{s,d}   (f32, pre-quantization)
    float sa[2][4] = {}, sd[2][4] = {};
#pragma unroll
    for (int j = 0; j < 4; j++) {
        int col = h * 64 + j * 16 + m16;
        float ws_ = a1s[col], wd_ = a1d[col];
#pragma unroll
        for (int i = 0; i < 2; i++)
#pragma unroll
            for (int reg = 0; reg < 4; reg++) {
                sa[i][reg] += acc[i][j][reg] * ws_;
                sd[i][reg] += acc[i][j][reg] * wd_;
            }
    }
#pragma unroll
    for (int m = 1; m < 16; m <<= 1)
#pragma unroll
        for (int i = 0; i < 2; i++)
#pragma unroll
            for (int reg = 0; reg < 4; reg++) {
                sa[i][reg] += __shfl_xor(sa[i][reg], m, 64);
                sd[i][reg] += __shfl_xor(sd[i][reg], m, 64);
            }
    if (m16 == 0)
#pragma unroll
        for (int i = 0; i < 2; i++)
#pragma unroll
            for (int reg = 0; reg < 4; reg++) {
                int row = m0 + wr + i * 16 + quad * 4 + reg;
                if (row < M) { als[row * 8 + h] = sa[i][reg]; ald[row * 8 + h] = sd[i][reg]; }
            }
    // hl fp8 pack (x8 scale; un-scaled by 0.125 in agg1's inv) -> LDS -> coalesced store
#pragma unroll
    for (int i = 0; i < 2; i++)
#pragma unroll
        for (int j = 0; j < 4; j++)
#pragma unroll
            for (int reg = 0; reg < 4; reg++) {
                int lr = wr + i * 16 + quad * 4 + reg;
                Cs[lr * 64 + j * 16 + m16] =
                    (unsigned char)(__builtin_amdgcn_cvt_pk_fp8_f32(acc[i][j][reg] * 8.f,
                                                                    0.f, 0, false) & 0xFF);
            }
    __syncthreads();
    for (int c = tid; c < 512; c += 256) {       // 512 x 16B chunks = 128 rows x 64B
        int row = c >> 2, off = c & 3;
        int grow = m0 + row;
        if (grow < M)
            *(uint4*)(hl8 + (size_t)grow * 512 + h * 64 + off * 16) =
                *(const uint4*)(Cs + c * 16);
    }
}

// ---------- agg1: post-GEMM edge aggregation; NO cross-lane ops in edge loop ----------
#define ACCP(e_, u_)                                      \
    {                                                     \
        f32x2 g0 = unpack8(u_.x), g1 = unpack8hi(u_.x);   \
        f32x2 g2 = unpack8(u_.y), g3 = unpack8hi(u_.y);   \
        acc[0] += (e_) * g0.x; acc[1] += (e_) * g0.y;     \
        acc[2] += (e_) * g1.x; acc[3] += (e_) * g1.y;     \
        acc[4] += (e_) * g2.x; acc[5] += (e_) * g2.y;     \
        acc[6] += (e_) * g3.x; acc[7] += (e_) * g3.y;     \
    }

__global__ __launch_bounds__(256) void agg1_k(const unsigned char* __restrict__ hl8,
                                              const float* __restrict__ als1,
                                              const float* __restrict__ ald1,
                                              const float* __restrict__ b1,
                                              const int* __restrict__ offs,
                                              const int* __restrict__ csr,
                                              unsigned char* __restrict__ h2q8, int N) {
    int wv = threadIdx.x >> 6;
    int t = threadIdx.x & 63;
    int n = blockIdx.x * 4 + wv;
    if (n >= N) return;
    int h = t >> 3;
    float dl = ald1[n * 8 + h];
    int p0 = offs[n], p1 = offs[n + 1];
    float acc[8] = {};
    float ssum = 0.f;
    int p = p0;
    for (; p + 4 <= p1; p += 4) {
        int sA = csr[p], sB = csr[p + 1], sC = csr[p + 2], sD = csr[p + 3];
        float eA = __expf(lrelu(als1[sA * 8 + h] + dl));
        float eB = __expf(lrelu(als1[sB * 8 + h] + dl));
        float eC = __expf(lrelu(als1[sC * 8 + h] + dl));
        float eD = __expf(lrelu(als1[sD * 8 + h] + dl));
        uint2 vA = *(const uint2*)(hl8 + (size_t)sA * 512 + t * 8);
        uint2 vB = *(const uint2*)(hl8 + (size_t)sB * 512 + t * 8);
        uint2 vC = *(const uint2*)(hl8 + (size_t)sC * 512 + t * 8);
        uint2 vD = *(const uint2*)(hl8 + (size_t)sD * 512 + t * 8);
        ssum += (eA + eB) + (eC + eD);
        ACCP(eA, vA);
        ACCP(eB, vB);
        ACCP(eC, vC);
        ACCP(eD, vD);
    }
    for (; p < p1; p++) {
        int sA = csr[p];
        float eA = __expf(lrelu(als1[sA * 8 + h] + dl));
        uint2 vA = *(const uint2*)(hl8 + (size_t)sA * 512 + t * 8);
        ssum += eA;
        ACCP(eA, vA);
    }
    float iv = 0.125f / (ssum + 1e-16f);   // undo hl x8 scale
    float4 bq0 = *(const float4*)(b1 + t * 8);
    float4 bq1 = *(const float4*)(b1 + t * 8 + 4);
    float r0 = elu(acc[0] * iv + bq0.x);
    float r1 = elu(acc[1] * iv + bq0.y);
    float r2 = elu(acc[2] * iv + bq0.z);
    float r3 = elu(acc[3] * iv + bq0.w);
    float r4 = elu(acc[4] * iv + bq1.x);
    float r5 = elu(acc[5] * iv + bq1.y);
    float r6 = elu(acc[6] * iv + bq1.z);
    float r7 = elu(acc[7] * iv + bq1.w);
    uint2 o;
    int d0 = __builtin_amdgcn_cvt_pk_fp8_f32(r0, r1, 0, false);
    o.x = (unsigned)__builtin_amdgcn_cvt_pk_fp8_f32(r2, r3, d0, true);
    int d1 = __builtin_amdgcn_cvt_pk_fp8_f32(r4, r5, 0, false);
    o.y = (unsigned)__builtin_amdgcn_cvt_pk_fp8_f32(r6, r7, d1, true);
    *(uint2*)(h2q8 + (size_t)n * 576 + t * 8) = o;
}

// ---------- gemm2 v2 (+fused attn2): direct-global operands, ZERO K-loop barriers ----------
// A fp8->bf16 converted in registers (exact); B (73KB) L2-resident; LDS only for
// the 4KB output repack so hl2q is written as full 64B lines.
__global__ __launch_bounds__(256) void gemm2_k(const unsigned char* __restrict__ Aq8,
                                               const unsigned short* __restrict__ Bt,
                                               const float* __restrict__ a2s,
                                               const float* __restrict__ a2d,
                                               unsigned char* __restrict__ hl2q,
                                               float* __restrict__ als2,
                                               float* __restrict__ ald2, int M) {
    __shared__ __align__(16) unsigned char Cs[64 * 64];    // 4KB output staging
    int tid = threadIdx.x;
    int m0 = blockIdx.x * 64;
    int w = tid >> 6, lane = tid & 63;
    int m16 = lane & 15, quad = lane >> 4;
    int arow = m0 + w * 16 + m16;
    const unsigned char* ap = Aq8 + (size_t)arow * 576 + quad * 8;
    bool aval = arow < M;
    f32x4 acc[4] = {};
#pragma unroll
    for (int kk = 0; kk < 576; kk += 32) {
        uint2 av = make_uint2(0u, 0u);
        if (aval) av = *(const uint2*)(ap + kk);
        uint4 aw;
        aw.x = bpack_trunc(unpack8(av.x));
        aw.y = bpack_trunc(unpack8hi(av.x));
        aw.z = bpack_trunc(unpack8(av.y));
        aw.w = bpack_trunc(unpack8hi(av.y));
        short8 a = *(short8*)&aw;
#pragma unroll
        for (int j = 0; j < 4; j++) {
            short8 b = *(const short8*)(Bt + (size_t)(j * 16 + m16) * 576 + kk + quad * 8);
            acc[j] = __builtin_amdgcn_mfma_f32_16x16x32_bf16(a, b, acc[j], 0, 0, 0);
        }
    }
    // fused attn2 (f32, pre-quantization)
    float sa[4] = {}, sd[4] = {};
#pragma unroll
    for (int j = 0; j < 4; j++) {
        int col = j * 16 + m16;
        float as_ = a2s[col], ad_ = a2d[col];
#pragma unroll
        for (int reg = 0; reg < 4; reg++) {
            sa[reg] += acc[j][reg] * as_;
            sd[reg] += acc[j][reg] * ad_;
        }
    }
#pragma unroll
    for (int m = 1; m < 16; m <<= 1)
#pragma unroll
        for (int reg = 0; reg < 4; reg++) {
            sa[reg] += __shfl_xor(sa[reg], m, 64);
            sd[reg] += __shfl_xor(sd[reg], m, 64);
        }
    if (m16 == 0)
#pragma unroll
        for (int reg = 0; reg < 4; reg++) {
            int row = m0 + w * 16 + quad * 4 + reg;
            if (row < M) { als2[row] = sa[reg]; ald2[row] = sd[reg]; }
        }
    // hl2q fp8 -> LDS repack -> coalesced 16B stores
#pragma unroll
    for (int j = 0; j < 4; j++)
#pragma unroll
        for (int reg = 0; reg < 4; reg++) {
            int lr = w * 16 + quad * 4 + reg;
            Cs[lr * 64 + j * 16 + m16] =
                (unsigned char)(__builtin_amdgcn_cvt_pk_fp8_f32(acc[j][reg], 0.f, 0, false) & 0xFF);
        }
    __syncthreads();
    if (tid < 256) {
        int row = tid >> 2, off = tid & 3;       // 64 rows x 4 chunks of 16B
        int grow = m0 + row;
        if (grow < M)
            *(uint4*)(hl2q + (size_t)grow * 64 + off * 16) = *(const uint4*)(Cs + tid * 16);
    }
}

// ---------- agg2: fused softmax+aggregate+elu over fp8 hl2 (plain gpart stores) ----------
__global__ __launch_bounds__(256) void agg2_k(const unsigned short* __restrict__ hl2q16,
                                              const float* __restrict__ als2,
                                              const float* __restrict__ ald2,
                                              const float* __restrict__ b2,
                                              const int* __restrict__ offs,
                                              const int* __restrict__ csr,
                                              float* __restrict__ gpart, int N) {
    __shared__ float red[512];
    int slot = threadIdx.x >> 5, l = threadIdx.x & 31;
    int n = blockIdx.x * 8 + slot;
    float v0 = 0.f, v1 = 0.f;
    if (n < N) {
        float dl = ald2[n];
        int p0 = offs[n], p1 = offs[n + 1];
        float a0 = 0.f, a1 = 0.f, ssum = 0.f;
        int p = p0;
        for (; p + 1 < p1; p += 2) {
            int sA = csr[p], sB = csr[p + 1];
            float lA = als2[sA], lB = als2[sB];
            unsigned hA = hl2q16[sA * 32 + l];
            unsigned hB = hl2q16[sB * 32 + l];
            float xA = __expf(lrelu(lA + dl));
            float xB = __expf(lrelu(lB + dl));
            ssum += xA + xB;
            f32x2 fA = unpack8(hA), fB = unpack8(hB);
            a0 += xA * fA.x + xB * fB.x;
            a1 += xA * fA.y + xB * fB.y;
        }
        if (p < p1) {
            int sA = csr[p];
            float xA = __expf(lrelu(als2[sA] + dl));
            ssum += xA;
            f32x2 fA = unpack8(hl2q16[sA * 32 + l]);
            a0 += xA * fA.x;
            a1 += xA * fA.y;
        }
        float inv = 1.f / (ssum + 1e-16f);
        v0 = elu(a0 * inv + b2[2 * l]);
        v1 = elu(a1 * inv + b2[2 * l + 1]);
    }
    red[slot * 64 + 2 * l] = v0;
    red[slot * 64 + 2 * l + 1] = v1;
    __syncthreads();
    if (threadIdx.x < 64) {
        float s = 0.f;
#pragma unroll
        for (int ss = 0; ss < 8; ss++) s += red[ss * 64 + threadIdx.x];
        gpart[(size_t)blockIdx.x * 64 + threadIdx.x] = s;
    }
}

// ---------- colred + final fused via last-block pattern (few blocks pay the fence) ----------
__global__ __launch_bounds__(256) void colredfinal_k(const float* __restrict__ gpart,
                                                     float* __restrict__ gsum,
                                                     int* __restrict__ done,
                                                     const float* __restrict__ fcw,
                                                     const float* __restrict__ fcb,
                                                     float* __restrict__ out,
                                                     int NBL, int N, int NCB) {
    __shared__ float red[256];
    __shared__ int isLast;
    int t = threadIdx.x;
    int c = t & 63, rg = t >> 6;
    int bend = blockIdx.x * 256 + 256; if (bend > NBL) bend = NBL;
    float acc = 0.f;
    for (int b = blockIdx.x * 256 + rg; b < bend; b += 4)
        acc += gpart[(size_t)b * 64 + c];
    red[t] = acc;
    __syncthreads();
    if (t < 64) atomicAdd(&gsum[c], red[c] + red[c + 64] + red[c + 128] + red[c + 192]);
    __threadfence();
    if (t == 0) {
        int old = atomicAdd(done, 1);
        isLast = (old == NCB - 1) ? 1 : 0;
    }
    __syncthreads();
    if (isLast) {
        __shared__ float g[64];
        if (t < 64) g[t] = atomicAdd(&gsum[t], 0.f) / (float)N;
        __syncthreads();
        if (t < 200) {
            float a = fcb[t];
#pragma unroll
            for (int cc = 0; cc < 64; cc++) a += g[cc] * fcw[cc * 200 + t];
            out[t] = a;
        }
    }
}

extern "C" void kernel_launch(void* const* d_in, const int* in_sizes, int n_in,
                              void* d_out, int out_size, void* d_ws, size_t ws_size,
                              hipStream_t stream) {
    const int* x = (const int*)d_in[0];
    const int* ei = (const int*)d_in[1];
    const int* et = (const int*)d_in[2];
    const float* ent_emb = (const float*)d_in[3];
    const float* rel_emb = (const float*)d_in[4];
    const float* W1 = (const float*)d_in[5];
    const float* a1s = (const float*)d_in[6];
    const float* a1d = (const float*)d_in[7];
    const float* b1 = (const float*)d_in[8];
    const float* W2 = (const float*)d_in[9];
    const float* a2s = (const float*)d_in[10];
    const float* a2d = (const float*)d_in[11];
    const float* b2 = (const float*)d_in[12];
    const float* fcw = (const float*)d_in[13];
    const float* fcb = (const float*)d_in[14];
    float* out = (float*)d_out;

    int N = in_sizes[0];
    int E = in_sizes[1] / 2;
    int Etot = E + N;
    int NB = (N + 255) / 256;     // scan blocks
    int NBL = (N + 7) / 8;        // agg2 blocks
    int NCB = (NBL + 255) / 256;  // colredfinal blocks
    int FB = (Etot + 255) / 256;  // fill blocks in merged dispatch
    int NMB = (N + 127) / 128;    // gemm1 m-blocks
    int NH1 = (N * 64 + 255) / 256;   // prep h1 blocks
    int DEGB = (Etot + 255) / 256;    // prep degree blocks

    char* p = (char*)d_ws;
    auto alloc = [&](size_t bytes) -> char* {
        char* r = p;
        p += (bytes + 255) & ~(size_t)255;
        return r;
    };
    unsigned* h1b2 = (unsigned*)alloc((size_t)N * 64 * 4);            // h1 bf16 pairs
    unsigned short* W1t = (unsigned short*)alloc((size_t)512 * 128 * 2);
    unsigned short* W2t = (unsigned short*)alloc((size_t)64 * 576 * 2);
    float* als1 = (float*)alloc((size_t)N * 8 * 4);
    float* ald1 = (float*)alloc((size_t)N * 8 * 4);
    unsigned char* hl8 = (unsigned char*)alloc((size_t)N * 512);      // hl fp8 x8 (15.4 MB)
    unsigned char* h2q8 = (unsigned char*)alloc((size_t)N * 576);     // h2 fp8 (17.3 MB)
    unsigned char* hl2q = (unsigned char*)alloc((size_t)N * 64);      // fp8 (1.9 MB)
    float* als2 = (float*)alloc((size_t)N * 4);
    float* ald2 = (float*)alloc((size_t)N * 4);
    float* gpart = (float*)alloc((size_t)NBL * 64 * 4);
    int* offs   = (int*)alloc((size_t)(N + 1) * 4);
    int* csr    = (int*)alloc((size_t)Etot * 4);
    // zero-init region: deg, cursor, gsum, done, bstate (contiguous)
    char* z0 = p;
    int* deg    = (int*)alloc((size_t)N * 4);
    int* cursor = (int*)alloc((size_t)N * 4);
    float* gsum = (float*)alloc(64 * 4);
    int* done   = (int*)alloc(4);
    int* bstate = (int*)alloc((size_t)NB * 4);
    size_t zbytes = (size_t)(p - z0);

    hipMemsetAsync(z0, 0, zbytes, stream);
    prep_k<<<NH1 + DEGB + 25, 256, 0, stream>>>(x, et, ei, ent_emb, rel_emb,
                                                W1, W2, h1b2, W1t, W2t, h2q8, deg,
                                                N, E, NH1, DEGB);
    scan_k<<<NB, 256, 0, stream>>>(deg, offs, bstate, N, Etot, NB);
    fillgemm1_k<<<FB + NMB * 8, 256, 0, stream>>>(ei, E, N, offs, cursor, csr,
                                                  (const unsigned short*)h1b2, W1t,
                                                  a1s, a1d, hl8, als1, ald1, FB, NMB);
    agg1_k<<<(N + 3) / 4, 256, 0, stream>>>(hl8, als1, ald1, b1, offs, csr, h2q8, N);
    gemm2_k<<<(N + 63) / 64, 256, 0, stream>>>(h2q8, W2t, a2s, a2d, hl2q, als2, ald2, N);
    agg2_k<<<NBL, 256, 0, stream>>>((const unsigned short*)hl2q, als2, ald2, b2, offs, csr, gpart, N);
    colredfinal_k<<<NCB, 256, 0, stream>>>(gpart, gsum, done, fcw, fcb, out, NBL, N, NCB);
}

// Round 9
// 244.128 us; speedup vs baseline: 1.0214x; 1.0214x over previous
//
#include <hip/hip_runtime.h>
#include <math.h>

#define NEG_SLOPE 0.2f

typedef __attribute__((ext_vector_type(8))) short short8;   // 8 bf16 (4 VGPRs)
typedef __attribute__((ext_vector_type(4))) float f32x4;
typedef __attribute__((ext_vector_type(2))) float f32x2;

// ---------- helpers ----------
__device__ __forceinline__ float lrelu(float v) { return v > 0.f ? v : NEG_SLOPE * v; }
__device__ __forceinline__ float elu(float v) { return v > 0.f ? v : (__expf(v) - 1.f); }
__device__ __forceinline__ unsigned short f2b(float f) {   // fp32 -> bf16 RNE
    unsigned u = __float_as_uint(f);
    return (unsigned short)((u + 0x7FFFu + ((u >> 16) & 1u)) >> 16);
}
__device__ __forceinline__ unsigned packb(float a, float b) {
    return ((unsigned)f2b(b) << 16) | (unsigned)f2b(a);
}
// fp8 e4m3 (OCP, gfx950 HW converts)
__device__ __forceinline__ unsigned short pack8(float a, float b) {
    return (unsigned short)(__builtin_amdgcn_cvt_pk_fp8_f32(a, b, 0, false) & 0xFFFF);
}
__device__ __forceinline__ f32x2 unpack8(unsigned v) {
    return __builtin_amdgcn_cvt_pk_f32_fp8((int)v, false);
}
__device__ __forceinline__ f32x2 unpack8hi(unsigned v) {
    return __builtin_amdgcn_cvt_pk_f32_fp8((int)v, true);
}
// two f32 -> packed bf16 pair by truncation (exact when inputs came from fp8)
__device__ __forceinline__ unsigned bpack_trunc(f32x2 f) {
    return (__float_as_uint(f.y) & 0xFFFF0000u) | (__float_as_uint(f.x) >> 16);
}
// LDS xor-swizzle: 16B-chunk o within row r
__device__ __forceinline__ int sw(int r, int o) { return (o ^ (r & 7)) << 3; }

// ---------- prep v2: block-range split, coalesced LDS-tiled transposes ----------
// blocks [0,NH1): h1 gather (1 job/thread); [NH1,NH1+DEGB): degree count;
// next 16: W1t 64x64 tile transposes; next 9: W2t tile transposes.
__global__ __launch_bounds__(256) void prep_k(const int* __restrict__ x,
                       const int* __restrict__ et, const int* __restrict__ ei,
                       const float* __restrict__ ent_emb, const float* __restrict__ rel_emb,
                       const float* __restrict__ W1, const float* __restrict__ W2,
                       unsigned* __restrict__ h1b2, unsigned short* __restrict__ W1t,
                       unsigned short* __restrict__ W2t, unsigned char* __restrict__ h2q8,
                       int* __restrict__ deg, int N, int E, int NH1, int DEGB) {
    __shared__ float T[64 * 65];
    int bid = blockIdx.x, tid = threadIdx.x;
    if (bid < NH1) {              // ---- h1 construction ----
        int t = bid * 256 + tid;
        if (t < N * 64) {         // pair j: cols 2j, 2j+1 of h1=[ent|rel]
            int n = t >> 6, j = t & 63;
            float v0, v1;
            if (j < 32) {
                const float* e = ent_emb + (size_t)x[n] * 64 + 2 * j;
                v0 = e[0]; v1 = e[1];
                // ent fp8 -> h2 cols 512+2j, 512+2j+1 (row stride 576 B)
                *(unsigned short*)(h2q8 + (size_t)n * 576 + 512 + 2 * j) = pack8(v0, v1);
            } else {
                const float* r = rel_emb + (size_t)et[n] * 64 + 2 * (j - 32);
                v0 = r[0]; v1 = r[1];
            }
            h1b2[t] = packb(v0, v1);
        }
        return;
    }
    bid -= NH1;
    if (bid < DEGB) {             // ---- degree (incl self-loop); deg[] pre-zeroed ----
        int e = bid * 256 + tid;
        if (e < E + N) {
            int dst = e < E ? ei[E + e] : e - E;
            atomicAdd(&deg[dst], 1);
        }
        return;
    }
    bid -= DEGB;
    if (bid < 16) {               // ---- W1t[n][k] = W1[k][n]; W1 [128][512] f32 ----
        int kt = bid >> 3, nt = bid & 7;
        for (int c = tid; c < 4096; c += 256) {
            int r = c >> 6, o = c & 63;    // r: k in tile, o: n in tile (coalesced read)
            T[o * 65 + r] = W1[(size_t)(kt * 64 + r) * 512 + nt * 64 + o];
        }
        __syncthreads();
        for (int c = tid; c < 4096; c += 256) {
            int n = c >> 6, k = c & 63;    // coalesced 128B-row writes
            W1t[(size_t)(nt * 64 + n) * 128 + kt * 64 + k] = f2b(T[n * 65 + k]);
        }
        return;
    }
    bid -= 16;
    if (bid < 9) {                // ---- W2t[n][k] = W2[k][n]; W2 [576][64] f32 ----
        int kt = bid;
        for (int c = tid; c < 4096; c += 256) {
            int r = c >> 6, o = c & 63;
            T[o * 65 + r] = W2[(size_t)(kt * 64 + r) * 64 + o];
        }
        __syncthreads();
        for (int c = tid; c < 4096; c += 256) {
            int n = c >> 6, k = c & 63;
            W2t[(size_t)n * 576 + kt * 64 + k] = f2b(T[n * 65 + k]);
        }
        return;
    }
}

// ---------- single-dispatch decoupled-lookback scan: deg -> offs ----------
__global__ __launch_bounds__(256) void scan_k(const int* __restrict__ deg,
                                              int* __restrict__ offs,
                                              int* __restrict__ bstate,
                                              int N, int Etot, int NB) {
    __shared__ int s[256];
    __shared__ int sbase;
    int b = blockIdx.x, t = threadIdx.x;
    int i = b * 256 + t;
    int v = (i < N) ? deg[i] : 0;
    s[t] = v;
    __syncthreads();
    for (int off = 1; off < 256; off <<= 1) {
        int tmp = (t >= off) ? s[t - off] : 0;
        __syncthreads();
        s[t] += tmp;
        __syncthreads();
    }
    int total = s[255];
    if (t == 0) {
        if (b == 0) {
            atomicExch(&bstate[0], (total << 2) | 2);
            sbase = 0;
        } else {
            atomicExch(&bstate[b], (total << 2) | 1);
            int run = 0;
            for (int p = b - 1; p >= 0;) {
                int stv;
                do { stv = atomicAdd(&bstate[p], 0); } while ((stv & 3) == 0);
                run += (stv >> 2);
                if ((stv & 3) == 2) break;
                p--;
            }
            atomicExch(&bstate[b], ((run + total) << 2) | 2);
            sbase = run;
        }
    }
    __syncthreads();
    if (i < N) offs[i] = sbase + s[t] - v;
    if (b == NB - 1 && t == 0) offs[N] = Etot;
}

// ---------- merged: CSR fill (blocks < FB) | gemm1 (+fused attn1) (blocks >= FB) ----------
// gemm1 path: MFMA operands loaded DIRECTLY from global (A-fragment = 16 contiguous
// bytes, register-reused across all 4 j; B is 131KB L2-resident). 8KB LDS only for
// the coalesced output repack.
__global__ __launch_bounds__(256) void fillgemm1_k(const int* __restrict__ ei, int E, int N,
                                                   const int* __restrict__ offs,
                                                   int* __restrict__ cursor,
                                                   int* __restrict__ csr,
                                                   const unsigned short* __restrict__ A,
                                                   const unsigned short* __restrict__ W1t,
                                                   const float* __restrict__ a1s,
                                                   const float* __restrict__ a1d,
                                                   unsigned char* __restrict__ hl8,
                                                   float* __restrict__ als,
                                                   float* __restrict__ ald,
                                                   int FB, int NMB) {
    __shared__ __align__(16) unsigned char Cs[128 * 64];   // 8KB output staging
    int bid = blockIdx.x;
    int tid = threadIdx.x;
    if (bid < FB) {               // ---- CSR fill path (no barriers) ----
        int e = bid * 256 + tid;
        if (e < E + N) {
            int src = e < E ? ei[e] : e - E;
            int dst = e < E ? ei[E + e] : e - E;
            int pos = offs[dst] + atomicAdd(&cursor[dst], 1);
            csr[pos] = src;
        }
        return;
    }
    // ---- gemm1 path ----
    int g = bid - FB;
    int h = g / NMB, mb = g - h * NMB;
    int m0 = mb * 128;
    int M = N;
    int w = tid >> 6, lane = tid & 63;
    int wr = w * 32;
    int m16 = lane & 15, quad = lane >> 4;
    f32x4 acc[2][4] = {};
#pragma unroll
    for (int kk = 0; kk < 128; kk += 32) {
        int col = kk + quad * 8;                 // lane's 8-elem fragment column
        short8 b[4];
#pragma unroll
        for (int j = 0; j < 4; j++)
            b[j] = *(const short8*)(W1t + (size_t)(h * 64 + j * 16 + m16) * 128 + col);
#pragma unroll
        for (int i = 0; i < 2; i++) {
            int r = m0 + wr + i * 16 + m16;
            short8 a = {};
            if (r < M) a = *(const short8*)(A + (size_t)r * 128 + col);
#pragma unroll
            for (int j = 0; j < 4; j++)
                acc[i][j] = __builtin_amdgcn_mfma_f32_16x16x32_bf16(a, b[j], acc[i][j], 0, 0, 0);
        }
    }
    // fused attn1: als/ald = sum_col hl * a1{s,d}   (f32, pre-quantization)
    float sa[2][4] = {}, sd[2][4] = {};
#pragma unroll
    for (int j = 0; j < 4; j++) {
        int col = h * 64 + j * 16 + m16;
        float ws_ = a1s[col], wd_ = a1d[col];
#pragma unroll
        for (int i = 0; i < 2; i++)
#pragma unroll
            for (int reg = 0; reg < 4; reg++) {
                sa[i][reg] += acc[i][j][reg] * ws_;
                sd[i][reg] += acc[i][j][reg] * wd_;
            }
    }
#pragma unroll
    for (int m = 1; m < 16; m <<= 1)
#pragma unroll
        for (int i = 0; i < 2; i++)
#pragma unroll
            for (int reg = 0; reg < 4; reg++) {
                sa[i][reg] += __shfl_xor(sa[i][reg], m, 64);
                sd[i][reg] += __shfl_xor(sd[i][reg], m, 64);
            }
    if (m16 == 0)
#pragma unroll
        for (int i = 0; i < 2; i++)
#pragma unroll
            for (int reg = 0; reg < 4; reg++) {
                int row = m0 + wr + i * 16 + quad * 4 + reg;
                if (row < M) { als[row * 8 + h] = sa[i][reg]; ald[row * 8 + h] = sd[i][reg]; }
            }
    // hl fp8 pack (x8 scale; un-scaled by 0.125 in agg1's inv) -> LDS -> coalesced store
#pragma unroll
    for (int i = 0; i < 2; i++)
#pragma unroll
        for (int j = 0; j < 4; j++)
#pragma unroll
            for (int reg = 0; reg < 4; reg++) {
                int lr = wr + i * 16 + quad * 4 + reg;
                Cs[lr * 64 + j * 16 + m16] =
                    (unsigned char)(__builtin_amdgcn_cvt_pk_fp8_f32(acc[i][j][reg] * 8.f,
                                                                    0.f, 0, false) & 0xFF);
            }
    __syncthreads();
    for (int c = tid; c < 512; c += 256) {       // 512 x 16B chunks = 128 rows x 64B
        int row = c >> 2, off = c & 3;
        int grow = m0 + row;
        if (grow < M)
            *(uint4*)(hl8 + (size_t)grow * 512 + h * 64 + off * 16) =
                *(const uint4*)(Cs + c * 16);
    }
}

// ---------- agg1: post-GEMM edge aggregation; NO cross-lane ops in edge loop ----------
#define ACCP(e_, u_)                                      \
    {                                                     \
        f32x2 g0 = unpack8(u_.x), g1 = unpack8hi(u_.x);   \
        f32x2 g2 = unpack8(u_.y), g3 = unpack8hi(u_.y);   \
        acc[0] += (e_) * g0.x; acc[1] += (e_) * g0.y;     \
        acc[2] += (e_) * g1.x; acc[3] += (e_) * g1.y;     \
        acc[4] += (e_) * g2.x; acc[5] += (e_) * g2.y;     \
        acc[6] += (e_) * g3.x; acc[7] += (e_) * g3.y;     \
    }

__global__ __launch_bounds__(256) void agg1_k(const unsigned char* __restrict__ hl8,
                                              const float* __restrict__ als1,
                                              const float* __restrict__ ald1,
                                              const float* __restrict__ b1,
                                              const int* __restrict__ offs,
                                              const int* __restrict__ csr,
                                              unsigned char* __restrict__ h2q8, int N) {
    int wv = threadIdx.x >> 6;
    int t = threadIdx.x & 63;
    int n = blockIdx.x * 4 + wv;
    if (n >= N) return;
    int h = t >> 3;
    float dl = ald1[n * 8 + h];
    int p0 = offs[n], p1 = offs[n + 1];
    float acc[8] = {};
    float ssum = 0.f;
    int p = p0;
    for (; p + 4 <= p1; p += 4) {
        int sA = csr[p], sB = csr[p + 1], sC = csr[p + 2], sD = csr[p + 3];
        float eA = __expf(lrelu(als1[sA * 8 + h] + dl));
        float eB = __expf(lrelu(als1[sB * 8 + h] + dl));
        float eC = __expf(lrelu(als1[sC * 8 + h] + dl));
        float eD = __expf(lrelu(als1[sD * 8 + h] + dl));
        uint2 vA = *(const uint2*)(hl8 + (size_t)sA * 512 + t * 8);
        uint2 vB = *(const uint2*)(hl8 + (size_t)sB * 512 + t * 8);
        uint2 vC = *(const uint2*)(hl8 + (size_t)sC * 512 + t * 8);
        uint2 vD = *(const uint2*)(hl8 + (size_t)sD * 512 + t * 8);
        ssum += (eA + eB) + (eC + eD);
        ACCP(eA, vA);
        ACCP(eB, vB);
        ACCP(eC, vC);
        ACCP(eD, vD);
    }
    for (; p < p1; p++) {
        int sA = csr[p];
        float eA = __expf(lrelu(als1[sA * 8 + h] + dl));
        uint2 vA = *(const uint2*)(hl8 + (size_t)sA * 512 + t * 8);
        ssum += eA;
        ACCP(eA, vA);
    }
    float iv = 0.125f / (ssum + 1e-16f);   // undo hl x8 scale
    float4 bq0 = *(const float4*)(b1 + t * 8);
    float4 bq1 = *(const float4*)(b1 + t * 8 + 4);
    float r0 = elu(acc[0] * iv + bq0.x);
    float r1 = elu(acc[1] * iv + bq0.y);
    float r2 = elu(acc[2] * iv + bq0.z);
    float r3 = elu(acc[3] * iv + bq0.w);
    float r4 = elu(acc[4] * iv + bq1.x);
    float r5 = elu(acc[5] * iv + bq1.y);
    float r6 = elu(acc[6] * iv + bq1.z);
    float r7 = elu(acc[7] * iv + bq1.w);
    uint2 o;
    int d0 = __builtin_amdgcn_cvt_pk_fp8_f32(r0, r1, 0, false);
    o.x = (unsigned)__builtin_amdgcn_cvt_pk_fp8_f32(r2, r3, d0, true);
    int d1 = __builtin_amdgcn_cvt_pk_fp8_f32(r4, r5, 0, false);
    o.y = (unsigned)__builtin_amdgcn_cvt_pk_fp8_f32(r6, r7, d1, true);
    *(uint2*)(h2q8 + (size_t)n * 576 + t * 8) = o;
}

// ---------- gemm2 v1 (+fused attn2): LDS-staged K-loop (B single-use -> staging pays),
// plus 4KB Cs output repack for coalesced hl2q stores ----------
__global__ __launch_bounds__(256) void gemm2_k(const unsigned char* __restrict__ Aq8,
                                               const unsigned short* __restrict__ Bt,
                                               const float* __restrict__ a2s,
                                               const float* __restrict__ a2d,
                                               unsigned char* __restrict__ hl2q,
                                               float* __restrict__ als2,
                                               float* __restrict__ ald2, int M) {
    __shared__ __align__(16) unsigned short As[64 * 64];
    __shared__ __align__(16) unsigned short Bs[64 * 64];
    __shared__ __align__(16) unsigned char Cs[64 * 64];    // 4KB output staging
    int tid = threadIdx.x;
    int m0 = blockIdx.x * 64;
    int w = tid >> 6, lane = tid & 63;
    int m16 = lane & 15, quad = lane >> 4;
    f32x4 acc[4] = {};
    for (int k0 = 0; k0 < 576; k0 += 64) {
        __syncthreads();
        {   // A: 64 rows x 64 fp8 -> bf16 (exact); exactly 256 chunks
            int r = tid >> 2, o = tid & 3;   // o: 16-fp8 chunk
            int gr = m0 + r;
            uint4 v = make_uint4(0u, 0u, 0u, 0u);
            if (gr < M) v = *(const uint4*)(Aq8 + (size_t)gr * 576 + k0 + o * 16);
            uint4 w0, w1;
            w0.x = bpack_trunc(unpack8(v.x));   w0.y = bpack_trunc(unpack8hi(v.x));
            w0.z = bpack_trunc(unpack8(v.y));   w0.w = bpack_trunc(unpack8hi(v.y));
            w1.x = bpack_trunc(unpack8(v.z));   w1.y = bpack_trunc(unpack8hi(v.z));
            w1.z = bpack_trunc(unpack8(v.w));   w1.w = bpack_trunc(unpack8hi(v.w));
            *(uint4*)(As + r * 64 + sw(r, 2 * o)) = w0;
            *(uint4*)(As + r * 64 + sw(r, 2 * o + 1)) = w1;
        }
        for (int c = tid; c < 512; c += 256) {
            int r = c >> 3, o = c & 7;
            uint4 v = *(const uint4*)(Bt + (size_t)r * 576 + k0 + o * 8);
            *(uint4*)(Bs + r * 64 + sw(r, o)) = v;
        }
        __syncthreads();
#pragma unroll
        for (int kk = 0; kk < 64; kk += 32) {
            int ob = (kk >> 3) + quad;
            int r = w * 16 + m16;
            short8 a = *(const short8*)(As + r * 64 + sw(r, ob));
#pragma unroll
            for (int j = 0; j < 4; j++) {
                int rb = j * 16 + m16;
                short8 b = *(const short8*)(Bs + rb * 64 + sw(rb, ob));
                acc[j] = __builtin_amdgcn_mfma_f32_16x16x32_bf16(a, b, acc[j], 0, 0, 0);
            }
        }
    }
    // fused attn2 (f32, pre-quantization)
    float sa[4] = {}, sd[4] = {};
#pragma unroll
    for (int j = 0; j < 4; j++) {
        int col = j * 16 + m16;
        float as_ = a2s[col], ad_ = a2d[col];
#pragma unroll
        for (int reg = 0; reg < 4; reg++) {
            sa[reg] += acc[j][reg] * as_;
            sd[reg] += acc[j][reg] * ad_;
        }
    }
#pragma unroll
    for (int m = 1; m < 16; m <<= 1)
#pragma unroll
        for (int reg = 0; reg < 4; reg++) {
            sa[reg] += __shfl_xor(sa[reg], m, 64);
            sd[reg] += __shfl_xor(sd[reg], m, 64);
        }
    if (m16 == 0)
#pragma unroll
        for (int reg = 0; reg < 4; reg++) {
            int row = m0 + w * 16 + quad * 4 + reg;
            if (row < M) { als2[row] = sa[reg]; ald2[row] = sd[reg]; }
        }
    // hl2q fp8 -> LDS repack -> coalesced 16B stores
#pragma unroll
    for (int j = 0; j < 4; j++)
#pragma unroll
        for (int reg = 0; reg < 4; reg++) {
            int lr = w * 16 + quad * 4 + reg;
            Cs[lr * 64 + j * 16 + m16] =
                (unsigned char)(__builtin_amdgcn_cvt_pk_fp8_f32(acc[j][reg], 0.f, 0, false) & 0xFF);
        }
    __syncthreads();
    {
        int row = tid >> 2, off = tid & 3;       // 64 rows x 4 chunks of 16B
        int grow = m0 + row;
        if (grow < M)
            *(uint4*)(hl2q + (size_t)grow * 64 + off * 16) = *(const uint4*)(Cs + tid * 16);
    }
}

// ---------- agg2: fused softmax+aggregate+elu over fp8 hl2 (plain gpart stores) ----------
__global__ __launch_bounds__(256) void agg2_k(const unsigned short* __restrict__ hl2q16,
                                              const float* __restrict__ als2,
                                              const float* __restrict__ ald2,
                                              const float* __restrict__ b2,
                                              const int* __restrict__ offs,
                                              const int* __restrict__ csr,
                                              float* __restrict__ gpart, int N) {
    __shared__ float red[512];
    int slot = threadIdx.x >> 5, l = threadIdx.x & 31;
    int n = blockIdx.x * 8 + slot;
    float v0 = 0.f, v1 = 0.f;
    if (n < N) {
        float dl = ald2[n];
        int p0 = offs[n], p1 = offs[n + 1];
        float a0 = 0.f, a1 = 0.f, ssum = 0.f;
        int p = p0;
        for (; p + 1 < p1; p += 2) {
            int sA = csr[p], sB = csr[p + 1];
            float lA = als2[sA], lB = als2[sB];
            unsigned hA = hl2q16[sA * 32 + l];
            unsigned hB = hl2q16[sB * 32 + l];
            float xA = __expf(lrelu(lA + dl));
            float xB = __expf(lrelu(lB + dl));
            ssum += xA + xB;
            f32x2 fA = unpack8(hA), fB = unpack8(hB);
            a0 += xA * fA.x + xB * fB.x;
            a1 += xA * fA.y + xB * fB.y;
        }
        if (p < p1) {
            int sA = csr[p];
            float xA = __expf(lrelu(als2[sA] + dl));
            ssum += xA;
            f32x2 fA = unpack8(hl2q16[sA * 32 + l]);
            a0 += xA * fA.x;
            a1 += xA * fA.y;
        }
        float inv = 1.f / (ssum + 1e-16f);
        v0 = elu(a0 * inv + b2[2 * l]);
        v1 = elu(a1 * inv + b2[2 * l + 1]);
    }
    red[slot * 64 + 2 * l] = v0;
    red[slot * 64 + 2 * l + 1] = v1;
    __syncthreads();
    if (threadIdx.x < 64) {
        float s = 0.f;
#pragma unroll
        for (int ss = 0; ss < 8; ss++) s += red[ss * 64 + threadIdx.x];
        gpart[(size_t)blockIdx.x * 64 + threadIdx.x] = s;
    }
}

// ---------- colred + final fused via last-block pattern (few blocks pay the fence) ----------
__global__ __launch_bounds__(256) void colredfinal_k(const float* __restrict__ gpart,
                                                     float* __restrict__ gsum,
                                                     int* __restrict__ done,
                                                     const float* __restrict__ fcw,
                                                     const float* __restrict__ fcb,
                                                     float* __restrict__ out,
                                                     int NBL, int N, int NCB) {
    __shared__ float red[256];
    __shared__ int isLast;
    int t = threadIdx.x;
    int c = t & 63, rg = t >> 6;
    int bend = blockIdx.x * 256 + 256; if (bend > NBL) bend = NBL;
    float acc = 0.f;
    for (int b = blockIdx.x * 256 + rg; b < bend; b += 4)
        acc += gpart[(size_t)b * 64 + c];
    red[t] = acc;
    __syncthreads();
    if (t < 64) atomicAdd(&gsum[c], red[c] + red[c + 64] + red[c + 128] + red[c + 192]);
    __threadfence();
    if (t == 0) {
        int old = atomicAdd(done, 1);
        isLast = (old == NCB - 1) ? 1 : 0;
    }
    __syncthreads();
    if (isLast) {
        __shared__ float g[64];
        if (t < 64) g[t] = atomicAdd(&gsum[t], 0.f) / (float)N;
        __syncthreads();
        if (t < 200) {
            float a = fcb[t];
#pragma unroll
            for (int cc = 0; cc < 64; cc++) a += g[cc] * fcw[cc * 200 + t];
            out[t] = a;
        }
    }
}

extern "C" void kernel_launch(void* const* d_in, const int* in_sizes, int n_in,
                              void* d_out, int out_size, void* d_ws, size_t ws_size,
                              hipStream_t stream) {
    const int* x = (const int*)d_in[0];
    const int* ei = (const int*)d_in[1];
    const int* et = (const int*)d_in[2];
    const float* ent_emb = (const float*)d_in[3];
    const float* rel_emb = (const float*)d_in[4];
    const float* W1 = (const float*)d_in[5];
    const float* a1s = (const float*)d_in[6];
    const float* a1d = (const float*)d_in[7];
    const float* b1 = (const float*)d_in[8];
    const float* W2 = (const float*)d_in[9];
    const float* a2s = (const float*)d_in[10];
    const float* a2d = (const float*)d_in[11];
    const float* b2 = (const float*)d_in[12];
    const float* fcw = (const float*)d_in[13];
    const float* fcb = (const float*)d_in[14];
    float* out = (float*)d_out;

    int N = in_sizes[0];
    int E = in_sizes[1] / 2;
    int Etot = E + N;
    int NB = (N + 255) / 256;     // scan blocks
    int NBL = (N + 7) / 8;        // agg2 blocks
    int NCB = (NBL + 255) / 256;  // colredfinal blocks
    int FB = (Etot + 255) / 256;  // fill blocks in merged dispatch
    int NMB = (N + 127) / 128;    // gemm1 m-blocks
    int NH1 = (N * 64 + 255) / 256;   // prep h1 blocks
    int DEGB = (Etot + 255) / 256;    // prep degree blocks

    char* p = (char*)d_ws;
    auto alloc = [&](size_t bytes) -> char* {
        char* r = p;
        p += (bytes + 255) & ~(size_t)255;
        return r;
    };
    unsigned* h1b2 = (unsigned*)alloc((size_t)N * 64 * 4);            // h1 bf16 pairs
    unsigned short* W1t = (unsigned short*)alloc((size_t)512 * 128 * 2);
    unsigned short* W2t = (unsigned short*)alloc((size_t)64 * 576 * 2);
    float* als1 = (float*)alloc((size_t)N * 8 * 4);
    float* ald1 = (float*)alloc((size_t)N * 8 * 4);
    unsigned char* hl8 = (unsigned char*)alloc((size_t)N * 512);      // hl fp8 x8 (15.4 MB)
    unsigned char* h2q8 = (unsigned char*)alloc((size_t)N * 576);     // h2 fp8 (17.3 MB)
    unsigned char* hl2q = (unsigned char*)alloc((size_t)N * 64);      // fp8 (1.9 MB)
    float* als2 = (float*)alloc((size_t)N * 4);
    float* ald2 = (float*)alloc((size_t)N * 4);
    float* gpart = (float*)alloc((size_t)NBL * 64 * 4);
    int* offs   = (int*)alloc((size_t)(N + 1) * 4);
    int* csr    = (int*)alloc((size_t)Etot * 4);
    // zero-init region: deg, cursor, gsum, done, bstate (contiguous)
    char* z0 = p;
    int* deg    = (int*)alloc((size_t)N * 4);
    int* cursor = (int*)alloc((size_t)N * 4);
    float* gsum = (float*)alloc(64 * 4);
    int* done   = (int*)alloc(4);
    int* bstate = (int*)alloc((size_t)NB * 4);
    size_t zbytes = (size_t)(p - z0);

    hipMemsetAsync(z0, 0, zbytes, stream);
    prep_k<<<NH1 + DEGB + 25, 256, 0, stream>>>(x, et, ei, ent_emb, rel_emb,
                                                W1, W2, h1b2, W1t, W2t, h2q8, deg,
                                                N, E, NH1, DEGB);
    scan_k<<<NB, 256, 0, stream>>>(deg, offs, bstate, N, Etot, NB);
    fillgemm1_k<<<FB + NMB * 8, 256, 0, stream>>>(ei, E, N, offs, cursor, csr,
                                                  (const unsigned short*)h1b2, W1t,
                                                  a1s, a1d, hl8, als1, ald1, FB, NMB);
    agg1_k<<<(N + 3) / 4, 256, 0, stream>>>(hl8, als1, ald1, b1, offs, csr, h2q8, N);
    gemm2_k<<<(N + 63) / 64, 256, 0, stream>>>(h2q8, W2t, a2s, a2d, hl2q, als2, ald2, N);
    agg2_k<<<NBL, 256, 0, stream>>>((const unsigned short*)hl2q, als2, ald2, b2, offs, csr, gpart, N);
    colredfinal_k<<<NCB, 256, 0, stream>>>(gpart, gsum, done, fcw, fcb, out, NBL, N, NCB);
}

// Round 10
// 235.295 us; speedup vs baseline: 1.0597x; 1.0375x over previous
//
#include <hip/hip_runtime.h>
#include <math.h>

#define NEG_SLOPE 0.2f

typedef __attribute__((ext_vector_type(8))) short short8;   // 8 bf16 (4 VGPRs)
typedef __attribute__((ext_vector_type(4))) float f32x4;
typedef __attribute__((ext_vector_type(2))) float f32x2;

// ---------- helpers ----------
__device__ __forceinline__ float lrelu(float v) { return v > 0.f ? v : NEG_SLOPE * v; }
__device__ __forceinline__ float elu(float v) { return v > 0.f ? v : (__expf(v) - 1.f); }
__device__ __forceinline__ unsigned short f2b(float f) {   // fp32 -> bf16 RNE
    unsigned u = __float_as_uint(f);
    return (unsigned short)((u + 0x7FFFu + ((u >> 16) & 1u)) >> 16);
}
__device__ __forceinline__ unsigned packb(float a, float b) {
    return ((unsigned)f2b(b) << 16) | (unsigned)f2b(a);
}
// fp8 e4m3 (OCP, gfx950 HW converts)
__device__ __forceinline__ unsigned short pack8(float a, float b) {
    return (unsigned short)(__builtin_amdgcn_cvt_pk_fp8_f32(a, b, 0, false) & 0xFFFF);
}
__device__ __forceinline__ f32x2 unpack8(unsigned v) {
    return __builtin_amdgcn_cvt_pk_f32_fp8((int)v, false);
}
__device__ __forceinline__ f32x2 unpack8hi(unsigned v) {
    return __builtin_amdgcn_cvt_pk_f32_fp8((int)v, true);
}
// two f32 -> packed bf16 pair by truncation (exact when inputs came from fp8)
__device__ __forceinline__ unsigned bpack_trunc(f32x2 f) {
    return (__float_as_uint(f.y) & 0xFFFF0000u) | (__float_as_uint(f.x) >> 16);
}
// LDS xor-swizzle: 16B-chunk o within row r
__device__ __forceinline__ int sw(int r, int o) { return (o ^ (r & 7)) << 3; }

// ---------- prep v1: h1 bf16 + ent fp8 tail of h2 + weight transposes + degree ----------
// (multi-job-per-thread layout deliberately kept: jobs overlap in-thread, measured
//  faster than the split-block "coalesced" v2 — r8 post-mortem)
__global__ void prep_k(const int* __restrict__ x, const int* __restrict__ et,
                       const int* __restrict__ ei,
                       const float* __restrict__ ent_emb, const float* __restrict__ rel_emb,
                       const float* __restrict__ W1, const float* __restrict__ W2,
                       unsigned* __restrict__ h1b2, unsigned short* __restrict__ W1t,
                       unsigned short* __restrict__ W2t, unsigned char* __restrict__ h2q8,
                       int* __restrict__ deg, int N, int E) {
    int t = blockIdx.x * blockDim.x + threadIdx.x;
    if (t < N * 64) {            // pair j: cols 2j, 2j+1 of h1=[ent|rel]
        int n = t >> 6, j = t & 63;
        float v0, v1;
        if (j < 32) {
            const float* e = ent_emb + (size_t)x[n] * 64 + 2 * j;
            v0 = e[0]; v1 = e[1];
            // ent fp8 -> h2 cols 512+2j, 512+2j+1 (row stride 576 B)
            *(unsigned short*)(h2q8 + (size_t)n * 576 + 512 + 2 * j) = pack8(v0, v1);
        } else {
            const float* r = rel_emb + (size_t)et[n] * 64 + 2 * (j - 32);
            v0 = r[0]; v1 = r[1];
        }
        h1b2[t] = packb(v0, v1);
    }
    if (t < 512 * 128) {  // W1t[n][k] = W1[k][n]
        int n = t >> 7, kk = t & 127;
        W1t[t] = f2b(W1[(size_t)kk * 512 + n]);
    }
    if (t < 64 * 576) {   // W2t[n][k] = W2[k][n]
        int n = t / 576, k = t % 576;
        W2t[t] = f2b(W2[(size_t)k * 64 + n]);
    }
    if (t < E + N) {      // degree (incl self-loop); deg[] zeroed by memset
        int dst = t < E ? ei[E + t] : t - E;
        atomicAdd(&deg[dst], 1);
    }
}

// ---------- single-dispatch decoupled-lookback scan: deg -> offs ----------
__global__ __launch_bounds__(256) void scan_k(const int* __restrict__ deg,
                                              int* __restrict__ offs,
                                              int* __restrict__ bstate,
                                              int N, int Etot, int NB) {
    __shared__ int s[256];
    __shared__ int sbase;
    int b = blockIdx.x, t = threadIdx.x;
    int i = b * 256 + t;
    int v = (i < N) ? deg[i] : 0;
    s[t] = v;
    __syncthreads();
    for (int off = 1; off < 256; off <<= 1) {
        int tmp = (t >= off) ? s[t - off] : 0;
        __syncthreads();
        s[t] += tmp;
        __syncthreads();
    }
    int total = s[255];
    if (t == 0) {
        if (b == 0) {
            atomicExch(&bstate[0], (total << 2) | 2);
            sbase = 0;
        } else {
            atomicExch(&bstate[b], (total << 2) | 1);
            int run = 0;
            for (int p = b - 1; p >= 0;) {
                int stv;
                do { stv = atomicAdd(&bstate[p], 0); } while ((stv & 3) == 0);
                run += (stv >> 2);
                if ((stv & 3) == 2) break;
                p--;
            }
            atomicExch(&bstate[b], ((run + total) << 2) | 2);
            sbase = run;
        }
    }
    __syncthreads();
    if (i < N) offs[i] = sbase + s[t] - v;
    if (b == NB - 1 && t == 0) offs[N] = Etot;
}

// ---------- merged: CSR fill (blocks < FB) | gemm1 (+fused attn1) (blocks >= FB) ----------
// v1: LDS-staged A/B (48KB) -- measured best in the full-pipeline total (r5).
__global__ __launch_bounds__(256) void fillgemm1_k(const int* __restrict__ ei, int E, int N,
                                                   const int* __restrict__ offs,
                                                   int* __restrict__ cursor,
                                                   int* __restrict__ csr,
                                                   const unsigned short* __restrict__ A,
                                                   const unsigned short* __restrict__ W1t,
                                                   const float* __restrict__ a1s,
                                                   const float* __restrict__ a1d,
                                                   unsigned char* __restrict__ hl8,
                                                   float* __restrict__ als,
                                                   float* __restrict__ ald,
                                                   int FB, int NMB) {
    __shared__ __align__(16) unsigned short As[128 * 128];
    __shared__ __align__(16) unsigned short Bs[64 * 128];
    int bid = blockIdx.x;
    int tid = threadIdx.x;
    if (bid < FB) {               // ---- CSR fill path (no barriers) ----
        int e = bid * 256 + tid;
        if (e < E + N) {
            int src = e < E ? ei[e] : e - E;
            int dst = e < E ? ei[E + e] : e - E;
            int pos = offs[dst] + atomicAdd(&cursor[dst], 1);
            csr[pos] = src;
        }
        return;
    }
    // ---- gemm1 path ----
    int g = bid - FB;
    int h = g / NMB, mb = g - h * NMB;
    int m0 = mb * 128;
    int M = N;
    for (int c = tid; c < 2048; c += 256) {
        int r = c >> 4, o = c & 15;
        int gr = m0 + r;
        uint4 v = make_uint4(0u, 0u, 0u, 0u);
        if (gr < M) v = *(const uint4*)(A + (size_t)gr * 128 + o * 8);
        *(uint4*)(As + r * 128 + sw(r, o)) = v;
    }
    for (int c = tid; c < 1024; c += 256) {
        int r = c >> 4, o = c & 15;
        uint4 v = *(const uint4*)(W1t + (size_t)(h * 64 + r) * 128 + o * 8);
        *(uint4*)(Bs + r * 128 + sw(r, o)) = v;
    }
    __syncthreads();
    int w = tid >> 6, lane = tid & 63;
    int wr = w * 32;
    int m16 = lane & 15, quad = lane >> 4;
    f32x4 acc[2][4] = {};
#pragma unroll
    for (int kk = 0; kk < 128; kk += 32) {
        int ob = (kk >> 3) + quad;
        short8 b[4];
#pragma unroll
        for (int j = 0; j < 4; j++) {
            int r = j * 16 + m16;
            b[j] = *(const short8*)(Bs + r * 128 + sw(r, ob));
        }
#pragma unroll
        for (int i = 0; i < 2; i++) {
            int r = wr + i * 16 + m16;
            short8 a = *(const short8*)(As + r * 128 + sw(r, ob));
#pragma unroll
            for (int j = 0; j < 4; j++)
                acc[i][j] = __builtin_amdgcn_mfma_f32_16x16x32_bf16(a, b[j], acc[i][j], 0, 0, 0);
        }
    }
    // hl fp8 write (x8 scale; un-scaled by 0.125 in agg1's inv)
#pragma unroll
    for (int i = 0; i < 2; i++)
#pragma unroll
        for (int j = 0; j < 4; j++)
#pragma unroll
            for (int reg = 0; reg < 4; reg++) {
                int row = m0 + wr + i * 16 + quad * 4 + reg;
                int col = h * 64 + j * 16 + m16;
                if (row < M)
                    hl8[(size_t)row * 512 + col] =
                        (unsigned char)(__builtin_amdgcn_cvt_pk_fp8_f32(acc[i][j][reg] * 8.f,
                                                                        0.f, 0, false) & 0xFF);
            }
    // fused attn1: als/ald = sum_col hl * a1{s,d}   (f32, pre-quantization)
    float sa[2][4] = {}, sd[2][4] = {};
#pragma unroll
    for (int j = 0; j < 4; j++) {
        int col = h * 64 + j * 16 + m16;
        float ws_ = a1s[col], wd_ = a1d[col];
#pragma unroll
        for (int i = 0; i < 2; i++)
#pragma unroll
            for (int reg = 0; reg < 4; reg++) {
                sa[i][reg] += acc[i][j][reg] * ws_;
                sd[i][reg] += acc[i][j][reg] * wd_;
            }
    }
#pragma unroll
    for (int m = 1; m < 16; m <<= 1)
#pragma unroll
        for (int i = 0; i < 2; i++)
#pragma unroll
            for (int reg = 0; reg < 4; reg++) {
                sa[i][reg] += __shfl_xor(sa[i][reg], m, 64);
                sd[i][reg] += __shfl_xor(sd[i][reg], m, 64);
            }
    if (m16 == 0)
#pragma unroll
        for (int i = 0; i < 2; i++)
#pragma unroll
            for (int reg = 0; reg < 4; reg++) {
                int row = m0 + wr + i * 16 + quad * 4 + reg;
                if (row < M) { als[row * 8 + h] = sa[i][reg]; ald[row * 8 + h] = sd[i][reg]; }
            }
}

// ---------- agg1: post-GEMM edge aggregation; NO cross-lane ops in edge loop ----------
#define ACCP(e_, u_)                                      \
    {                                                     \
        f32x2 g0 = unpack8(u_.x), g1 = unpack8hi(u_.x);   \
        f32x2 g2 = unpack8(u_.y), g3 = unpack8hi(u_.y);   \
        acc[0] += (e_) * g0.x; acc[1] += (e_) * g0.y;     \
        acc[2] += (e_) * g1.x; acc[3] += (e_) * g1.y;     \
        acc[4] += (e_) * g2.x; acc[5] += (e_) * g2.y;     \
        acc[6] += (e_) * g3.x; acc[7] += (e_) * g3.y;     \
    }

__global__ __launch_bounds__(256) void agg1_k(const unsigned char* __restrict__ hl8,
                                              const float* __restrict__ als1,
                                              const float* __restrict__ ald1,
                                              const float* __restrict__ b1,
                                              const int* __restrict__ offs,
                                              const int* __restrict__ csr,
                                              unsigned char* __restrict__ h2q8, int N) {
    int wv = threadIdx.x >> 6;
    int t = threadIdx.x & 63;
    int n = blockIdx.x * 4 + wv;
    if (n >= N) return;
    int h = t >> 3;
    float dl = ald1[n * 8 + h];
    int p0 = offs[n], p1 = offs[n + 1];
    float acc[8] = {};
    float ssum = 0.f;
    int p = p0;
    for (; p + 4 <= p1; p += 4) {
        int sA = csr[p], sB = csr[p + 1], sC = csr[p + 2], sD = csr[p + 3];
        float eA = __expf(lrelu(als1[sA * 8 + h] + dl));
        float eB = __expf(lrelu(als1[sB * 8 + h] + dl));
        float eC = __expf(lrelu(als1[sC * 8 + h] + dl));
        float eD = __expf(lrelu(als1[sD * 8 + h] + dl));
        uint2 vA = *(const uint2*)(hl8 + (size_t)sA * 512 + t * 8);
        uint2 vB = *(const uint2*)(hl8 + (size_t)sB * 512 + t * 8);
        uint2 vC = *(const uint2*)(hl8 + (size_t)sC * 512 + t * 8);
        uint2 vD = *(const uint2*)(hl8 + (size_t)sD * 512 + t * 8);
        ssum += (eA + eB) + (eC + eD);
        ACCP(eA, vA);
        ACCP(eB, vB);
        ACCP(eC, vC);
        ACCP(eD, vD);
    }
    for (; p < p1; p++) {
        int sA = csr[p];
        float eA = __expf(lrelu(als1[sA * 8 + h] + dl));
        uint2 vA = *(const uint2*)(hl8 + (size_t)sA * 512 + t * 8);
        ssum += eA;
        ACCP(eA, vA);
    }
    float iv = 0.125f / (ssum + 1e-16f);   // undo hl x8 scale
    float4 bq0 = *(const float4*)(b1 + t * 8);
    float4 bq1 = *(const float4*)(b1 + t * 8 + 4);
    float r0 = elu(acc[0] * iv + bq0.x);
    float r1 = elu(acc[1] * iv + bq0.y);
    float r2 = elu(acc[2] * iv + bq0.z);
    float r3 = elu(acc[3] * iv + bq0.w);
    float r4 = elu(acc[4] * iv + bq1.x);
    float r5 = elu(acc[5] * iv + bq1.y);
    float r6 = elu(acc[6] * iv + bq1.z);
    float r7 = elu(acc[7] * iv + bq1.w);
    uint2 o;
    int d0 = __builtin_amdgcn_cvt_pk_fp8_f32(r0, r1, 0, false);
    o.x = (unsigned)__builtin_amdgcn_cvt_pk_fp8_f32(r2, r3, d0, true);
    int d1 = __builtin_amdgcn_cvt_pk_fp8_f32(r4, r5, 0, false);
    o.y = (unsigned)__builtin_amdgcn_cvt_pk_fp8_f32(r6, r7, d1, true);
    *(uint2*)(h2q8 + (size_t)n * 576 + t * 8) = o;
}

// ---------- gemm2 v1 (+fused attn2): LDS-staged K-loop + Cs output repack ----------
__global__ __launch_bounds__(256) void gemm2_k(const unsigned char* __restrict__ Aq8,
                                               const unsigned short* __restrict__ Bt,
                                               const float* __restrict__ a2s,
                                               const float* __restrict__ a2d,
                                               unsigned char* __restrict__ hl2q,
                                               float* __restrict__ als2,
                                               float* __restrict__ ald2, int M) {
    __shared__ __align__(16) unsigned short As[64 * 64];
    __shared__ __align__(16) unsigned short Bs[64 * 64];
    __shared__ __align__(16) unsigned char Cs[64 * 64];    // 4KB output staging
    int tid = threadIdx.x;
    int m0 = blockIdx.x * 64;
    int w = tid >> 6, lane = tid & 63;
    int m16 = lane & 15, quad = lane >> 4;
    f32x4 acc[4] = {};
    for (int k0 = 0; k0 < 576; k0 += 64) {
        __syncthreads();
        {   // A: 64 rows x 64 fp8 -> bf16 (exact); exactly 256 chunks
            int r = tid >> 2, o = tid & 3;   // o: 16-fp8 chunk
            int gr = m0 + r;
            uint4 v = make_uint4(0u, 0u, 0u, 0u);
            if (gr < M) v = *(const uint4*)(Aq8 + (size_t)gr * 576 + k0 + o * 16);
            uint4 w0, w1;
            w0.x = bpack_trunc(unpack8(v.x));   w0.y = bpack_trunc(unpack8hi(v.x));
            w0.z = bpack_trunc(unpack8(v.y));   w0.w = bpack_trunc(unpack8hi(v.y));
            w1.x = bpack_trunc(unpack8(v.z));   w1.y = bpack_trunc(unpack8hi(v.z));
            w1.z = bpack_trunc(unpack8(v.w));   w1.w = bpack_trunc(unpack8hi(v.w));
            *(uint4*)(As + r * 64 + sw(r, 2 * o)) = w0;
            *(uint4*)(As + r * 64 + sw(r, 2 * o + 1)) = w1;
        }
        for (int c = tid; c < 512; c += 256) {
            int r = c >> 3, o = c & 7;
            uint4 v = *(const uint4*)(Bt + (size_t)r * 576 + k0 + o * 8);
            *(uint4*)(Bs + r * 64 + sw(r, o)) = v;
        }
        __syncthreads();
#pragma unroll
        for (int kk = 0; kk < 64; kk += 32) {
            int ob = (kk >> 3) + quad;
            int r = w * 16 + m16;
            short8 a = *(const short8*)(As + r * 64 + sw(r, ob));
#pragma unroll
            for (int j = 0; j < 4; j++) {
                int rb = j * 16 + m16;
                short8 b = *(const short8*)(Bs + rb * 64 + sw(rb, ob));
                acc[j] = __builtin_amdgcn_mfma_f32_16x16x32_bf16(a, b, acc[j], 0, 0, 0);
            }
        }
    }
    // fused attn2 (f32, pre-quantization)
    float sa[4] = {}, sd[4] = {};
#pragma unroll
    for (int j = 0; j < 4; j++) {
        int col = j * 16 + m16;
        float as_ = a2s[col], ad_ = a2d[col];
#pragma unroll
        for (int reg = 0; reg < 4; reg++) {
            sa[reg] += acc[j][reg] * as_;
            sd[reg] += acc[j][reg] * ad_;
        }
    }
#pragma unroll
    for (int m = 1; m < 16; m <<= 1)
#pragma unroll
        for (int reg = 0; reg < 4; reg++) {
            sa[reg] += __shfl_xor(sa[reg], m, 64);
            sd[reg] += __shfl_xor(sd[reg], m, 64);
        }
    if (m16 == 0)
#pragma unroll
        for (int reg = 0; reg < 4; reg++) {
            int row = m0 + w * 16 + quad * 4 + reg;
            if (row < M) { als2[row] = sa[reg]; ald2[row] = sd[reg]; }
        }
    // hl2q fp8 -> LDS repack -> coalesced 16B stores (verified pattern, r8)
#pragma unroll
    for (int j = 0; j < 4; j++)
#pragma unroll
        for (int reg = 0; reg < 4; reg++) {
            int lr = w * 16 + quad * 4 + reg;
            Cs[lr * 64 + j * 16 + m16] =
                (unsigned char)(__builtin_amdgcn_cvt_pk_fp8_f32(acc[j][reg], 0.f, 0, false) & 0xFF);
        }
    __syncthreads();
    {
        int row = tid >> 2, off = tid & 3;       // 64 rows x 4 chunks of 16B
        int grow = m0 + row;
        if (grow < M)
            *(uint4*)(hl2q + (size_t)grow * 64 + off * 16) = *(const uint4*)(Cs + tid * 16);
    }
}

// ---------- agg2: fused softmax+aggregate+elu over fp8 hl2 (plain gpart stores) ----------
__global__ __launch_bounds__(256) void agg2_k(const unsigned short* __restrict__ hl2q16,
                                              const float* __restrict__ als2,
                                              const float* __restrict__ ald2,
                                              const float* __restrict__ b2,
                                              const int* __restrict__ offs,
                                              const int* __restrict__ csr,
                                              float* __restrict__ gpart, int N) {
    __shared__ float red[512];
    int slot = threadIdx.x >> 5, l = threadIdx.x & 31;
    int n = blockIdx.x * 8 + slot;
    float v0 = 0.f, v1 = 0.f;
    if (n < N) {
        float dl = ald2[n];
        int p0 = offs[n], p1 = offs[n + 1];
        float a0 = 0.f, a1 = 0.f, ssum = 0.f;
        int p = p0;
        for (; p + 1 < p1; p += 2) {
            int sA = csr[p], sB = csr[p + 1];
            float lA = als2[sA], lB = als2[sB];
            unsigned hA = hl2q16[sA * 32 + l];
            unsigned hB = hl2q16[sB * 32 + l];
            float xA = __expf(lrelu(lA + dl));
            float xB = __expf(lrelu(lB + dl));
            ssum += xA + xB;
            f32x2 fA = unpack8(hA), fB = unpack8(hB);
            a0 += xA * fA.x + xB * fB.x;
            a1 += xA * fA.y + xB * fB.y;
        }
        if (p < p1) {
            int sA = csr[p];
            float xA = __expf(lrelu(als2[sA] + dl));
            ssum += xA;
            f32x2 fA = unpack8(hl2q16[sA * 32 + l]);
            a0 += xA * fA.x;
            a1 += xA * fA.y;
        }
        float inv = 1.f / (ssum + 1e-16f);
        v0 = elu(a0 * inv + b2[2 * l]);
        v1 = elu(a1 * inv + b2[2 * l + 1]);
    }
    red[slot * 64 + 2 * l] = v0;
    red[slot * 64 + 2 * l + 1] = v1;
    __syncthreads();
    if (threadIdx.x < 64) {
        float s = 0.f;
#pragma unroll
        for (int ss = 0; ss < 8; ss++) s += red[ss * 64 + threadIdx.x];
        gpart[(size_t)blockIdx.x * 64 + threadIdx.x] = s;
    }
}

// ---------- colred + final fused via last-block pattern (few blocks pay the fence) ----------
__global__ __launch_bounds__(256) void colredfinal_k(const float* __restrict__ gpart,
                                                     float* __restrict__ gsum,
                                                     int* __restrict__ done,
                                                     const float* __restrict__ fcw,
                                                     const float* __restrict__ fcb,
                                                     float* __restrict__ out,
                                                     int NBL, int N, int NCB) {
    __shared__ float red[256];
    __shared__ int isLast;
    int t = threadIdx.x;
    int c = t & 63, rg = t >> 6;
    int bend = blockIdx.x * 256 + 256; if (bend > NBL) bend = NBL;
    float acc = 0.f;
    for (int b = blockIdx.x * 256 + rg; b < bend; b += 4)
        acc += gpart[(size_t)b * 64 + c];
    red[t] = acc;
    __syncthreads();
    if (t < 64) atomicAdd(&gsum[c], red[c] + red[c + 64] + red[c + 128] + red[c + 192]);
    __threadfence();
    if (t == 0) {
        int old = atomicAdd(done, 1);
        isLast = (old == NCB - 1) ? 1 : 0;
    }
    __syncthreads();
    if (isLast) {
        __shared__ float g[64];
        if (t < 64) g[t] = atomicAdd(&gsum[t], 0.f) / (float)N;
        __syncthreads();
        if (t < 200) {
            float a = fcb[t];
#pragma unroll
            for (int cc = 0; cc < 64; cc++) a += g[cc] * fcw[cc * 200 + t];
            out[t] = a;
        }
    }
}

extern "C" void kernel_launch(void* const* d_in, const int* in_sizes, int n_in,
                              void* d_out, int out_size, void* d_ws, size_t ws_size,
                              hipStream_t stream) {
    const int* x = (const int*)d_in[0];
    const int* ei = (const int*)d_in[1];
    const int* et = (const int*)d_in[2];
    const float* ent_emb = (const float*)d_in[3];
    const float* rel_emb = (const float*)d_in[4];
    const float* W1 = (const float*)d_in[5];
    const float* a1s = (const float*)d_in[6];
    const float* a1d = (const float*)d_in[7];
    const float* b1 = (const float*)d_in[8];
    const float* W2 = (const float*)d_in[9];
    const float* a2s = (const float*)d_in[10];
    const float* a2d = (const float*)d_in[11];
    const float* b2 = (const float*)d_in[12];
    const float* fcw = (const float*)d_in[13];
    const float* fcb = (const float*)d_in[14];
    float* out = (float*)d_out;

    int N = in_sizes[0];
    int E = in_sizes[1] / 2;
    int Etot = E + N;
    int NB = (N + 255) / 256;     // scan blocks
    int NBL = (N + 7) / 8;        // agg2 blocks
    int NCB = (NBL + 255) / 256;  // colredfinal blocks
    int FB = (Etot + 255) / 256;  // fill blocks in merged dispatch
    int NMB = (N + 127) / 128;    // gemm1 m-blocks

    char* p = (char*)d_ws;
    auto alloc = [&](size_t bytes) -> char* {
        char* r = p;
        p += (bytes + 255) & ~(size_t)255;
        return r;
    };
    unsigned* h1b2 = (unsigned*)alloc((size_t)N * 64 * 4);            // h1 bf16 pairs
    unsigned short* W1t = (unsigned short*)alloc((size_t)512 * 128 * 2);
    unsigned short* W2t = (unsigned short*)alloc((size_t)64 * 576 * 2);
    float* als1 = (float*)alloc((size_t)N * 8 * 4);
    float* ald1 = (float*)alloc((size_t)N * 8 * 4);
    unsigned char* hl8 = (unsigned char*)alloc((size_t)N * 512);      // hl fp8 x8 (15.4 MB)
    unsigned char* h2q8 = (unsigned char*)alloc((size_t)N * 576);     // h2 fp8 (17.3 MB)
    unsigned char* hl2q = (unsigned char*)alloc((size_t)N * 64);      // fp8 (1.9 MB)
    float* als2 = (float*)alloc((size_t)N * 4);
    float* ald2 = (float*)alloc((size_t)N * 4);
    float* gpart = (float*)alloc((size_t)NBL * 64 * 4);
    int* offs   = (int*)alloc((size_t)(N + 1) * 4);
    int* csr    = (int*)alloc((size_t)Etot * 4);
    // zero-init region: deg, cursor, gsum, done, bstate (contiguous)
    char* z0 = p;
    int* deg    = (int*)alloc((size_t)N * 4);
    int* cursor = (int*)alloc((size_t)N * 4);
    float* gsum = (float*)alloc(64 * 4);
    int* done   = (int*)alloc(4);
    int* bstate = (int*)alloc((size_t)NB * 4);
    size_t zbytes = (size_t)(p - z0);

    int tb = 256;
    hipMemsetAsync(z0, 0, zbytes, stream);
    prep_k<<<(N * 64 + tb - 1) / tb, tb, 0, stream>>>(x, et, ei, ent_emb, rel_emb,
                                                      W1, W2, h1b2, W1t, W2t, h2q8, deg, N, E);
    scan_k<<<NB, 256, 0, stream>>>(deg, offs, bstate, N, Etot, NB);
    fillgemm1_k<<<FB + NMB * 8, 256, 0, stream>>>(ei, E, N, offs, cursor, csr,
                                                  (const unsigned short*)h1b2, W1t,
                                                  a1s, a1d, hl8, als1, ald1, FB, NMB);
    agg1_k<<<(N + 3) / 4, 256, 0, stream>>>(hl8, als1, ald1, b1, offs, csr, h2q8, N);
    gemm2_k<<<(N + 63) / 64, 256, 0, stream>>>(h2q8, W2t, a2s, a2d, hl2q, als2, ald2, N);
    agg2_k<<<NBL, 256, 0, stream>>>((const unsigned short*)hl2q, als2, ald2, b2, offs, csr, gpart, N);
    colredfinal_k<<<NCB, 256, 0, stream>>>(gpart, gsum, done, fcw, fcb, out, NBL, N, NCB);
}

// Round 11
// 231.709 us; speedup vs baseline: 1.0761x; 1.0155x over previous
//
#include <hip/hip_runtime.h>
#include <math.h>

#define NEG_SLOPE 0.2f

typedef __attribute__((ext_vector_type(8))) short short8;   // 8 bf16 (4 VGPRs)
typedef __attribute__((ext_vector_type(4))) float f32x4;
typedef __attribute__((ext_vector_type(2))) float f32x2;

// ---------- helpers ----------
__device__ __forceinline__ float lrelu(float v) { return v > 0.f ? v : NEG_SLOPE * v; }
__device__ __forceinline__ float elu(float v) { return v > 0.f ? v : (__expf(v) - 1.f); }
__device__ __forceinline__ unsigned short f2b(float f) {   // fp32 -> bf16 RNE
    unsigned u = __float_as_uint(f);
    return (unsigned short)((u + 0x7FFFu + ((u >> 16) & 1u)) >> 16);
}
__device__ __forceinline__ unsigned packb(float a, float b) {
    return ((unsigned)f2b(b) << 16) | (unsigned)f2b(a);
}
// fp8 e4m3 (OCP, gfx950 HW converts)
__device__ __forceinline__ unsigned short pack8(float a, float b) {
    return (unsigned short)(__builtin_amdgcn_cvt_pk_fp8_f32(a, b, 0, false) & 0xFFFF);
}
__device__ __forceinline__ f32x2 unpack8(unsigned v) {
    return __builtin_amdgcn_cvt_pk_f32_fp8((int)v, false);
}
__device__ __forceinline__ f32x2 unpack8hi(unsigned v) {
    return __builtin_amdgcn_cvt_pk_f32_fp8((int)v, true);
}
// two f32 -> packed bf16 pair by truncation (exact when inputs came from fp8)
__device__ __forceinline__ unsigned bpack_trunc(f32x2 f) {
    return (__float_as_uint(f.y) & 0xFFFF0000u) | (__float_as_uint(f.x) >> 16);
}
// LDS xor-swizzle: 16B-chunk o within row r
__device__ __forceinline__ int sw(int r, int o) { return (o ^ (r & 7)) << 3; }

// ---------- prep v1: h1 bf16 + ent fp8 tail of h2 + weight transposes + degree ----------
// (multi-job-per-thread layout deliberately kept: jobs overlap in-thread, measured
//  faster than the split-block "coalesced" v2 — r8 post-mortem)
__global__ void prep_k(const int* __restrict__ x, const int* __restrict__ et,
                       const int* __restrict__ ei,
                       const float* __restrict__ ent_emb, const float* __restrict__ rel_emb,
                       const float* __restrict__ W1, const float* __restrict__ W2,
                       unsigned* __restrict__ h1b2, unsigned short* __restrict__ W1t,
                       unsigned short* __restrict__ W2t, unsigned char* __restrict__ h2q8,
                       int* __restrict__ deg, int N, int E) {
    int t = blockIdx.x * blockDim.x + threadIdx.x;
    if (t < N * 64) {            // pair j: cols 2j, 2j+1 of h1=[ent|rel]
        int n = t >> 6, j = t & 63;
        float v0, v1;
        if (j < 32) {
            const float* e = ent_emb + (size_t)x[n] * 64 + 2 * j;
            v0 = e[0]; v1 = e[1];
            // ent fp8 -> h2 cols 512+2j, 512+2j+1 (row stride 576 B)
            *(unsigned short*)(h2q8 + (size_t)n * 576 + 512 + 2 * j) = pack8(v0, v1);
        } else {
            const float* r = rel_emb + (size_t)et[n] * 64 + 2 * (j - 32);
            v0 = r[0]; v1 = r[1];
        }
        h1b2[t] = packb(v0, v1);
    }
    if (t < 512 * 128) {  // W1t[n][k] = W1[k][n]
        int n = t >> 7, kk = t & 127;
        W1t[t] = f2b(W1[(size_t)kk * 512 + n]);
    }
    if (t < 64 * 576) {   // W2t[n][k] = W2[k][n]
        int n = t / 576, k = t % 576;
        W2t[t] = f2b(W2[(size_t)k * 64 + n]);
    }
    if (t < E + N) {      // degree (incl self-loop); deg[] zeroed by memset
        int dst = t < E ? ei[E + t] : t - E;
        atomicAdd(&deg[dst], 1);
    }
}

// ---------- single-dispatch decoupled-lookback scan: deg -> offs ----------
__global__ __launch_bounds__(256) void scan_k(const int* __restrict__ deg,
                                              int* __restrict__ offs,
                                              int* __restrict__ bstate,
                                              int N, int Etot, int NB) {
    __shared__ int s[256];
    __shared__ int sbase;
    int b = blockIdx.x, t = threadIdx.x;
    int i = b * 256 + t;
    int v = (i < N) ? deg[i] : 0;
    s[t] = v;
    __syncthreads();
    for (int off = 1; off < 256; off <<= 1) {
        int tmp = (t >= off) ? s[t - off] : 0;
        __syncthreads();
        s[t] += tmp;
        __syncthreads();
    }
    int total = s[255];
    if (t == 0) {
        if (b == 0) {
            atomicExch(&bstate[0], (total << 2) | 2);
            sbase = 0;
        } else {
            atomicExch(&bstate[b], (total << 2) | 1);
            int run = 0;
            for (int p = b - 1; p >= 0;) {
                int stv;
                do { stv = atomicAdd(&bstate[p], 0); } while ((stv & 3) == 0);
                run += (stv >> 2);
                if ((stv & 3) == 2) break;
                p--;
            }
            atomicExch(&bstate[b], ((run + total) << 2) | 2);
            sbase = run;
        }
    }
    __syncthreads();
    if (i < N) offs[i] = sbase + s[t] - v;
    if (b == NB - 1 && t == 0) offs[N] = Etot;
}

// ---------- merged: gemm1 (+fused attn1) (blocks < GB) | CSR fill (blocks >= GB) ----------
// LPT ordering: LONG gemm1 blocks dispatch first, SHORT fill blocks pack the tail.
__global__ __launch_bounds__(256) void fillgemm1_k(const int* __restrict__ ei, int E, int N,
                                                   const int* __restrict__ offs,
                                                   int* __restrict__ cursor,
                                                   int* __restrict__ csr,
                                                   const unsigned short* __restrict__ A,
                                                   const unsigned short* __restrict__ W1t,
                                                   const float* __restrict__ a1s,
                                                   const float* __restrict__ a1d,
                                                   unsigned char* __restrict__ hl8,
                                                   float* __restrict__ als,
                                                   float* __restrict__ ald,
                                                   int GB, int NMB) {
    __shared__ __align__(16) unsigned short As[128 * 128];
    __shared__ __align__(16) unsigned short Bs[64 * 128];
    int bid = blockIdx.x;
    int tid = threadIdx.x;
    if (bid >= GB) {              // ---- CSR fill path (no barriers), tail-packed ----
        int e = (bid - GB) * 256 + tid;
        if (e < E + N) {
            int src = e < E ? ei[e] : e - E;
            int dst = e < E ? ei[E + e] : e - E;
            int pos = offs[dst] + atomicAdd(&cursor[dst], 1);
            csr[pos] = src;
        }
        return;
    }
    // ---- gemm1 path ----
    int g = bid;
    int h = g / NMB, mb = g - h * NMB;
    int m0 = mb * 128;
    int M = N;
    for (int c = tid; c < 2048; c += 256) {
        int r = c >> 4, o = c & 15;
        int gr = m0 + r;
        uint4 v = make_uint4(0u, 0u, 0u, 0u);
        if (gr < M) v = *(const uint4*)(A + (size_t)gr * 128 + o * 8);
        *(uint4*)(As + r * 128 + sw(r, o)) = v;
    }
    for (int c = tid; c < 1024; c += 256) {
        int r = c >> 4, o = c & 15;
        uint4 v = *(const uint4*)(W1t + (size_t)(h * 64 + r) * 128 + o * 8);
        *(uint4*)(Bs + r * 128 + sw(r, o)) = v;
    }
    __syncthreads();
    int w = tid >> 6, lane = tid & 63;
    int wr = w * 32;
    int m16 = lane & 15, quad = lane >> 4;
    f32x4 acc[2][4] = {};
#pragma unroll
    for (int kk = 0; kk < 128; kk += 32) {
        int ob = (kk >> 3) + quad;
        short8 b[4];
#pragma unroll
        for (int j = 0; j < 4; j++) {
            int r = j * 16 + m16;
            b[j] = *(const short8*)(Bs + r * 128 + sw(r, ob));
        }
#pragma unroll
        for (int i = 0; i < 2; i++) {
            int r = wr + i * 16 + m16;
            short8 a = *(const short8*)(As + r * 128 + sw(r, ob));
#pragma unroll
            for (int j = 0; j < 4; j++)
                acc[i][j] = __builtin_amdgcn_mfma_f32_16x16x32_bf16(a, b[j], acc[i][j], 0, 0, 0);
        }
    }
    // hl fp8 write (x8 scale; un-scaled by 0.125 in agg1's inv)
#pragma unroll
    for (int i = 0; i < 2; i++)
#pragma unroll
        for (int j = 0; j < 4; j++)
#pragma unroll
            for (int reg = 0; reg < 4; reg++) {
                int row = m0 + wr + i * 16 + quad * 4 + reg;
                int col = h * 64 + j * 16 + m16;
                if (row < M)
                    hl8[(size_t)row * 512 + col] =
                        (unsigned char)(__builtin_amdgcn_cvt_pk_fp8_f32(acc[i][j][reg] * 8.f,
                                                                        0.f, 0, false) & 0xFF);
            }
    // fused attn1: als/ald = sum_col hl * a1{s,d}   (f32, pre-quantization)
    float sa[2][4] = {}, sd[2][4] = {};
#pragma unroll
    for (int j = 0; j < 4; j++) {
        int col = h * 64 + j * 16 + m16;
        float ws_ = a1s[col], wd_ = a1d[col];
#pragma unroll
        for (int i = 0; i < 2; i++)
#pragma unroll
            for (int reg = 0; reg < 4; reg++) {
                sa[i][reg] += acc[i][j][reg] * ws_;
                sd[i][reg] += acc[i][j][reg] * wd_;
            }
    }
#pragma unroll
    for (int m = 1; m < 16; m <<= 1)
#pragma unroll
        for (int i = 0; i < 2; i++)
#pragma unroll
            for (int reg = 0; reg < 4; reg++) {
                sa[i][reg] += __shfl_xor(sa[i][reg], m, 64);
                sd[i][reg] += __shfl_xor(sd[i][reg], m, 64);
            }
    if (m16 == 0)
#pragma unroll
        for (int i = 0; i < 2; i++)
#pragma unroll
            for (int reg = 0; reg < 4; reg++) {
                int row = m0 + wr + i * 16 + quad * 4 + reg;
                if (row < M) { als[row * 8 + h] = sa[i][reg]; ald[row * 8 + h] = sd[i][reg]; }
            }
}

// ---------- agg1: post-GEMM edge aggregation; NO cross-lane ops in edge loop ----------
#define ACCP(e_, u_)                                      \
    {                                                     \
        f32x2 g0 = unpack8(u_.x), g1 = unpack8hi(u_.x);   \
        f32x2 g2 = unpack8(u_.y), g3 = unpack8hi(u_.y);   \
        acc[0] += (e_) * g0.x; acc[1] += (e_) * g0.y;     \
        acc[2] += (e_) * g1.x; acc[3] += (e_) * g1.y;     \
        acc[4] += (e_) * g2.x; acc[5] += (e_) * g2.y;     \
        acc[6] += (e_) * g3.x; acc[7] += (e_) * g3.y;     \
    }

__global__ __launch_bounds__(256) void agg1_k(const unsigned char* __restrict__ hl8,
                                              const float* __restrict__ als1,
                                              const float* __restrict__ ald1,
                                              const float* __restrict__ b1,
                                              const int* __restrict__ offs,
                                              const int* __restrict__ csr,
                                              unsigned char* __restrict__ h2q8, int N) {
    int wv = threadIdx.x >> 6;
    int t = threadIdx.x & 63;
    int n = blockIdx.x * 4 + wv;
    if (n >= N) return;
    int h = t >> 3;
    float dl = ald1[n * 8 + h];
    float4 bq0 = *(const float4*)(b1 + t * 8);       // hoisted: no tail-dependent load
    float4 bq1 = *(const float4*)(b1 + t * 8 + 4);
    int p0 = offs[n], p1 = offs[n + 1];
    float acc[8] = {};
    float ssum = 0.f;
    int p = p0;
    for (; p + 4 <= p1; p += 4) {
        int sA = csr[p], sB = csr[p + 1], sC = csr[p + 2], sD = csr[p + 3];
        float eA = __expf(lrelu(als1[sA * 8 + h] + dl));
        float eB = __expf(lrelu(als1[sB * 8 + h] + dl));
        float eC = __expf(lrelu(als1[sC * 8 + h] + dl));
        float eD = __expf(lrelu(als1[sD * 8 + h] + dl));
        uint2 vA = *(const uint2*)(hl8 + (size_t)sA * 512 + t * 8);
        uint2 vB = *(const uint2*)(hl8 + (size_t)sB * 512 + t * 8);
        uint2 vC = *(const uint2*)(hl8 + (size_t)sC * 512 + t * 8);
        uint2 vD = *(const uint2*)(hl8 + (size_t)sD * 512 + t * 8);
        ssum += (eA + eB) + (eC + eD);
        ACCP(eA, vA);
        ACCP(eB, vB);
        ACCP(eC, vC);
        ACCP(eD, vD);
    }
    for (; p < p1; p++) {
        int sA = csr[p];
        float eA = __expf(lrelu(als1[sA * 8 + h] + dl));
        uint2 vA = *(const uint2*)(hl8 + (size_t)sA * 512 + t * 8);
        ssum += eA;
        ACCP(eA, vA);
    }
    float iv = 0.125f / (ssum + 1e-16f);   // undo hl x8 scale
    float r0 = elu(acc[0] * iv + bq0.x);
    float r1 = elu(acc[1] * iv + bq0.y);
    float r2 = elu(acc[2] * iv + bq0.z);
    float r3 = elu(acc[3] * iv + bq0.w);
    float r4 = elu(acc[4] * iv + bq1.x);
    float r5 = elu(acc[5] * iv + bq1.y);
    float r6 = elu(acc[6] * iv + bq1.z);
    float r7 = elu(acc[7] * iv + bq1.w);
    uint2 o;
    int d0 = __builtin_amdgcn_cvt_pk_fp8_f32(r0, r1, 0, false);
    o.x = (unsigned)__builtin_amdgcn_cvt_pk_fp8_f32(r2, r3, d0, true);
    int d1 = __builtin_amdgcn_cvt_pk_fp8_f32(r4, r5, 0, false);
    o.y = (unsigned)__builtin_amdgcn_cvt_pk_fp8_f32(r6, r7, d1, true);
    *(uint2*)(h2q8 + (size_t)n * 576 + t * 8) = o;
}

// ---------- gemm2 v1 (+fused attn2): LDS-staged K-loop + Cs output repack ----------
__global__ __launch_bounds__(256) void gemm2_k(const unsigned char* __restrict__ Aq8,
                                               const unsigned short* __restrict__ Bt,
                                               const float* __restrict__ a2s,
                                               const float* __restrict__ a2d,
                                               unsigned char* __restrict__ hl2q,
                                               float* __restrict__ als2,
                                               float* __restrict__ ald2, int M) {
    __shared__ __align__(16) unsigned short As[64 * 64];
    __shared__ __align__(16) unsigned short Bs[64 * 64];
    __shared__ __align__(16) unsigned char Cs[64 * 64];    // 4KB output staging
    int tid = threadIdx.x;
    int m0 = blockIdx.x * 64;
    int w = tid >> 6, lane = tid & 63;
    int m16 = lane & 15, quad = lane >> 4;
    f32x4 acc[4] = {};
    for (int k0 = 0; k0 < 576; k0 += 64) {
        __syncthreads();
        {   // A: 64 rows x 64 fp8 -> bf16 (exact); exactly 256 chunks
            int r = tid >> 2, o = tid & 3;   // o: 16-fp8 chunk
            int gr = m0 + r;
            uint4 v = make_uint4(0u, 0u, 0u, 0u);
            if (gr < M) v = *(const uint4*)(Aq8 + (size_t)gr * 576 + k0 + o * 16);
            uint4 w0, w1;
            w0.x = bpack_trunc(unpack8(v.x));   w0.y = bpack_trunc(unpack8hi(v.x));
            w0.z = bpack_trunc(unpack8(v.y));   w0.w = bpack_trunc(unpack8hi(v.y));
            w1.x = bpack_trunc(unpack8(v.z));   w1.y = bpack_trunc(unpack8hi(v.z));
            w1.z = bpack_trunc(unpack8(v.w));   w1.w = bpack_trunc(unpack8hi(v.w));
            *(uint4*)(As + r * 64 + sw(r, 2 * o)) = w0;
            *(uint4*)(As + r * 64 + sw(r, 2 * o + 1)) = w1;
        }
        for (int c = tid; c < 512; c += 256) {
            int r = c >> 3, o = c & 7;
            uint4 v = *(const uint4*)(Bt + (size_t)r * 576 + k0 + o * 8);
            *(uint4*)(Bs + r * 64 + sw(r, o)) = v;
        }
        __syncthreads();
#pragma unroll
        for (int kk = 0; kk < 64; kk += 32) {
            int ob = (kk >> 3) + quad;
            int r = w * 16 + m16;
            short8 a = *(const short8*)(As + r * 64 + sw(r, ob));
#pragma unroll
            for (int j = 0; j < 4; j++) {
                int rb = j * 16 + m16;
                short8 b = *(const short8*)(Bs + rb * 64 + sw(rb, ob));
                acc[j] = __builtin_amdgcn_mfma_f32_16x16x32_bf16(a, b, acc[j], 0, 0, 0);
            }
        }
    }
    // fused attn2 (f32, pre-quantization)
    float sa[4] = {}, sd[4] = {};
#pragma unroll
    for (int j = 0; j < 4; j++) {
        int col = j * 16 + m16;
        float as_ = a2s[col], ad_ = a2d[col];
#pragma unroll
        for (int reg = 0; reg < 4; reg++) {
            sa[reg] += acc[j][reg] * as_;
            sd[reg] += acc[j][reg] * ad_;
        }
    }
#pragma unroll
    for (int m = 1; m < 16; m <<= 1)
#pragma unroll
        for (int reg = 0; reg < 4; reg++) {
            sa[reg] += __shfl_xor(sa[reg], m, 64);
            sd[reg] += __shfl_xor(sd[reg], m, 64);
        }
    if (m16 == 0)
#pragma unroll
        for (int reg = 0; reg < 4; reg++) {
            int row = m0 + w * 16 + quad * 4 + reg;
            if (row < M) { als2[row] = sa[reg]; ald2[row] = sd[reg]; }
        }
    // hl2q fp8 -> LDS repack -> coalesced 16B stores
#pragma unroll
    for (int j = 0; j < 4; j++)
#pragma unroll
        for (int reg = 0; reg < 4; reg++) {
            int lr = w * 16 + quad * 4 + reg;
            Cs[lr * 64 + j * 16 + m16] =
                (unsigned char)(__builtin_amdgcn_cvt_pk_fp8_f32(acc[j][reg], 0.f, 0, false) & 0xFF);
        }
    __syncthreads();
    {
        int row = tid >> 2, off = tid & 3;       // 64 rows x 4 chunks of 16B
        int grow = m0 + row;
        if (grow < M)
            *(uint4*)(hl2q + (size_t)grow * 64 + off * 16) = *(const uint4*)(Cs + tid * 16);
    }
}

// ---------- agg2: fused softmax+aggregate+elu over fp8 hl2 (4-edge unroll) ----------
__global__ __launch_bounds__(256) void agg2_k(const unsigned short* __restrict__ hl2q16,
                                              const float* __restrict__ als2,
                                              const float* __restrict__ ald2,
                                              const float* __restrict__ b2,
                                              const int* __restrict__ offs,
                                              const int* __restrict__ csr,
                                              float* __restrict__ gpart, int N) {
    __shared__ float red[512];
    int slot = threadIdx.x >> 5, l = threadIdx.x & 31;
    int n = blockIdx.x * 8 + slot;
    float v0 = 0.f, v1 = 0.f;
    if (n < N) {
        float dl = ald2[n];
        int p0 = offs[n], p1 = offs[n + 1];
        float a0 = 0.f, a1 = 0.f, ssum = 0.f;
        int p = p0;
        for (; p + 4 <= p1; p += 4) {        // 4 independent chains (agg1's verified MLP)
            int sA = csr[p], sB = csr[p + 1], sC = csr[p + 2], sD = csr[p + 3];
            float xA = __expf(lrelu(als2[sA] + dl));
            float xB = __expf(lrelu(als2[sB] + dl));
            float xC = __expf(lrelu(als2[sC] + dl));
            float xD = __expf(lrelu(als2[sD] + dl));
            unsigned hA = hl2q16[sA * 32 + l];
            unsigned hB = hl2q16[sB * 32 + l];
            unsigned hC = hl2q16[sC * 32 + l];
            unsigned hD = hl2q16[sD * 32 + l];
            ssum += (xA + xB) + (xC + xD);
            f32x2 fA = unpack8(hA), fB = unpack8(hB), fC = unpack8(hC), fD = unpack8(hD);
            a0 += xA * fA.x + xB * fB.x + xC * fC.x + xD * fD.x;
            a1 += xA * fA.y + xB * fB.y + xC * fC.y + xD * fD.y;
        }
        for (; p < p1; p++) {
            int sA = csr[p];
            float xA = __expf(lrelu(als2[sA] + dl));
            ssum += xA;
            f32x2 fA = unpack8(hl2q16[sA * 32 + l]);
            a0 += xA * fA.x;
            a1 += xA * fA.y;
        }
        float inv = 1.f / (ssum + 1e-16f);
        v0 = elu(a0 * inv + b2[2 * l]);
        v1 = elu(a1 * inv + b2[2 * l + 1]);
    }
    red[slot * 64 + 2 * l] = v0;
    red[slot * 64 + 2 * l + 1] = v1;
    __syncthreads();
    if (threadIdx.x < 64) {
        float s = 0.f;
#pragma unroll
        for (int ss = 0; ss < 8; ss++) s += red[ss * 64 + threadIdx.x];
        gpart[(size_t)blockIdx.x * 64 + threadIdx.x] = s;
    }
}

// ---------- colred + final fused via last-block pattern (few blocks pay the fence) ----------
__global__ __launch_bounds__(256) void colredfinal_k(const float* __restrict__ gpart,
                                                     float* __restrict__ gsum,
                                                     int* __restrict__ done,
                                                     const float* __restrict__ fcw,
                                                     const float* __restrict__ fcb,
                                                     float* __restrict__ out,
                                                     int NBL, int N, int NCB) {
    __shared__ float red[256];
    __shared__ int isLast;
    int t = threadIdx.x;
    int c = t & 63, rg = t >> 6;
    int bend = blockIdx.x * 256 + 256; if (bend > NBL) bend = NBL;
    float acc = 0.f;
    for (int b = blockIdx.x * 256 + rg; b < bend; b += 4)
        acc += gpart[(size_t)b * 64 + c];
    red[t] = acc;
    __syncthreads();
    if (t < 64) atomicAdd(&gsum[c], red[c] + red[c + 64] + red[c + 128] + red[c + 192]);
    __threadfence();
    if (t == 0) {
        int old = atomicAdd(done, 1);
        isLast = (old == NCB - 1) ? 1 : 0;
    }
    __syncthreads();
    if (isLast) {
        __shared__ float g[64];
        if (t < 64) g[t] = atomicAdd(&gsum[t], 0.f) / (float)N;
        __syncthreads();
        if (t < 200) {
            float a = fcb[t];
#pragma unroll
            for (int cc = 0; cc < 64; cc++) a += g[cc] * fcw[cc * 200 + t];
            out[t] = a;
        }
    }
}

extern "C" void kernel_launch(void* const* d_in, const int* in_sizes, int n_in,
                              void* d_out, int out_size, void* d_ws, size_t ws_size,
                              hipStream_t stream) {
    const int* x = (const int*)d_in[0];
    const int* ei = (const int*)d_in[1];
    const int* et = (const int*)d_in[2];
    const float* ent_emb = (const float*)d_in[3];
    const float* rel_emb = (const float*)d_in[4];
    const float* W1 = (const float*)d_in[5];
    const float* a1s = (const float*)d_in[6];
    const float* a1d = (const float*)d_in[7];
    const float* b1 = (const float*)d_in[8];
    const float* W2 = (const float*)d_in[9];
    const float* a2s = (const float*)d_in[10];
    const float* a2d = (const float*)d_in[11];
    const float* b2 = (const float*)d_in[12];
    const float* fcw = (const float*)d_in[13];
    const float* fcb = (const float*)d_in[14];
    float* out = (float*)d_out;

    int N = in_sizes[0];
    int E = in_sizes[1] / 2;
    int Etot = E + N;
    int NB = (N + 255) / 256;     // scan blocks
    int NBL = (N + 7) / 8;        // agg2 blocks
    int NCB = (NBL + 255) / 256;  // colredfinal blocks
    int FB = (Etot + 255) / 256;  // fill blocks in merged dispatch
    int NMB = (N + 127) / 128;    // gemm1 m-blocks
    int GB = NMB * 8;             // gemm1 blocks (dispatched first; fill packs the tail)

    char* p = (char*)d_ws;
    auto alloc = [&](size_t bytes) -> char* {
        char* r = p;
        p += (bytes + 255) & ~(size_t)255;
        return r;
    };
    unsigned* h1b2 = (unsigned*)alloc((size_t)N * 64 * 4);            // h1 bf16 pairs
    unsigned short* W1t = (unsigned short*)alloc((size_t)512 * 128 * 2);
    unsigned short* W2t = (unsigned short*)alloc((size_t)64 * 576 * 2);
    float* als1 = (float*)alloc((size_t)N * 8 * 4);
    float* ald1 = (float*)alloc((size_t)N * 8 * 4);
    unsigned char* hl8 = (unsigned char*)alloc((size_t)N * 512);      // hl fp8 x8 (15.4 MB)
    unsigned char* h2q8 = (unsigned char*)alloc((size_t)N * 576);     // h2 fp8 (17.3 MB)
    unsigned char* hl2q = (unsigned char*)alloc((size_t)N * 64);      // fp8 (1.9 MB)
    float* als2 = (float*)alloc((size_t)N * 4);
    float* ald2 = (float*)alloc((size_t)N * 4);
    float* gpart = (float*)alloc((size_t)NBL * 64 * 4);
    int* offs   = (int*)alloc((size_t)(N + 1) * 4);
    int* csr    = (int*)alloc((size_t)Etot * 4);
    // zero-init region: deg, cursor, gsum, done, bstate (contiguous)
    char* z0 = p;
    int* deg    = (int*)alloc((size_t)N * 4);
    int* cursor = (int*)alloc((size_t)N * 4);
    float* gsum = (float*)alloc(64 * 4);
    int* done   = (int*)alloc(4);
    int* bstate = (int*)alloc((size_t)NB * 4);
    size_t zbytes = (size_t)(p - z0);

    int tb = 256;
    hipMemsetAsync(z0, 0, zbytes, stream);
    prep_k<<<(N * 64 + tb - 1) / tb, tb, 0, stream>>>(x, et, ei, ent_emb, rel_emb,
                                                      W1, W2, h1b2, W1t, W2t, h2q8, deg, N, E);
    scan_k<<<NB, 256, 0, stream>>>(deg, offs, bstate, N, Etot, NB);
    fillgemm1_k<<<GB + FB, 256, 0, stream>>>(ei, E, N, offs, cursor, csr,
                                             (const unsigned short*)h1b2, W1t,
                                             a1s, a1d, hl8, als1, ald1, GB, NMB);
    agg1_k<<<(N + 3) / 4, 256, 0, stream>>>(hl8, als1, ald1, b1, offs, csr, h2q8, N);
    gemm2_k<<<(N + 63) / 64, 256, 0, stream>>>(h2q8, W2t, a2s, a2d, hl2q, als2, ald2, N);
    agg2_k<<<NBL, 256, 0, stream>>>((const unsigned short*)hl2q, als2, ald2, b2, offs, csr, gpart, N);
    colredfinal_k<<<NCB, 256, 0, stream>>>(gpart, gsum, done, fcw, fcb, out, NBL, N, NCB);
}